// Round 5
// baseline (640.755 us; speedup 1.0000x reference)
//
#include <hip/hip_runtime.h>
#include <hip/hip_bf16.h>
#include <math.h>

#define HIDDEN 1024
#define NEXP 8
#define TOPK 2
#define INTER 1408
#define SINTER 2816
#define NTOK 4096
#define NROWS (NTOK * TOPK) /* 8192 routed rows */
#define NPANEL 10           /* 8 routed + 2 shared halves */
#define TROWS 16384         /* NROWS + 2*NTOK */

typedef unsigned short ushort_t;
typedef __attribute__((ext_vector_type(8))) short short8;
typedef __attribute__((ext_vector_type(4))) float f32x4;

__device__ __forceinline__ ushort_t f2bf(float f) {
    unsigned int b = __float_as_uint(f);
    unsigned int r = (b + 0x7FFFu + ((b >> 16) & 1u)) >> 16;
    return (ushort_t)r;
}
__device__ __forceinline__ float silu_f(float g) {
    return g * (1.0f / (1.0f + __expf(-g)));
}
__device__ __forceinline__ int imin(int a, int b) { return a < b ? a : b; }

#define GLDS16(gp, lp) __builtin_amdgcn_global_load_lds(                     \
    (const __attribute__((address_space(1))) void*)(gp),                     \
    (__attribute__((address_space(3))) void*)(lp), 16, 0, 0)

// bijective XCD-chunked block swizzle (total blocks % 8 == 0)
__device__ __forceinline__ void swz3(int& bx, int& by, int& bz) {
    int nb = gridDim.x, mb = gridDim.y;
    int total = nb * mb * gridDim.z;
    int orig = (blockIdx.z * mb + blockIdx.y) * nb + blockIdx.x;
    int cpx = total >> 3;
    int w = (orig & 7) * cpx + (orig >> 3);
    bz = w / (nb * mb);
    int rem = w - bz * (nb * mb);
    by = rem / nb;
    bx = rem - by * nb;
}

// ---------------- fp32 -> bf16 elementwise (x) ----------------
__global__ void conv_x(const float* __restrict__ src, ushort_t* __restrict__ dst) {
    int i = (blockIdx.x * 256 + threadIdx.x) * 4;
    float4 v = *reinterpret_cast<const float4*>(&src[i]);
    union { ushort_t h[4]; unsigned long long ll; } p;
    p.h[0] = f2bf(v.x); p.h[1] = f2bf(v.y); p.h[2] = f2bf(v.z); p.h[3] = f2bf(v.w);
    *reinterpret_cast<unsigned long long*>(&dst[i]) = p.ll;
}

// ---- fp32 [R][C] -> bf16 [C][R] transpose-convert -------------------------
__global__ void tconv(const float* __restrict__ src, ushort_t* __restrict__ dst,
                      int R, int C, long sstride, long dstride) {
    src += (size_t)blockIdx.z * sstride;
    dst += (size_t)blockIdx.z * dstride;
    __shared__ float tile[32][33];
    int ct = blockIdx.x * 32, rt = blockIdx.y * 32;
    int tx = threadIdx.x, ty = threadIdx.y;  // 32 x 8
#pragma unroll
    for (int i = 0; i < 4; i++)
        tile[ty + 8 * i][tx] = src[(size_t)(rt + ty + 8 * i) * C + ct + tx];
    __syncthreads();
#pragma unroll
    for (int i = 0; i < 4; i++)
        dst[(size_t)(ct + ty + 8 * i) * R + rt + tx] = f2bf(tile[tx][ty + 8 * i]);
}

// ---------------- gate: logits -> softmax -> top2 -> normalized weights ----
__global__ void gate_kernel(const float* __restrict__ x, const float* __restrict__ gw,
                            int* __restrict__ top_i, float* __restrict__ top_w) {
    int t = blockIdx.x;
    int lane = threadIdx.x;
    const float* xr = x + (size_t)t * HIDDEN;
    float acc[NEXP];
#pragma unroll
    for (int e = 0; e < NEXP; e++) acc[e] = 0.f;
    for (int j = 0; j < HIDDEN / 64; j++) {
        float xv = xr[lane + 64 * j];
#pragma unroll
        for (int e = 0; e < NEXP; e++)
            acc[e] = fmaf(xv, gw[e * HIDDEN + lane + 64 * j], acc[e]);
    }
#pragma unroll
    for (int e = 0; e < NEXP; e++) {
        float v = acc[e];
        for (int off = 32; off > 0; off >>= 1) v += __shfl_xor(v, off, 64);
        acc[e] = v;
    }
    if (lane == 0) {
        float mx = acc[0];
        for (int e = 1; e < NEXP; e++) mx = fmaxf(mx, acc[e]);
        float s[NEXP];
        float sum = 0.f;
        for (int e = 0; e < NEXP; e++) { s[e] = __expf(acc[e] - mx); sum += s[e]; }
        float inv = 1.0f / sum;
        for (int e = 0; e < NEXP; e++) s[e] *= inv;
        int e0 = 0;
        for (int e = 1; e < NEXP; e++) if (s[e] > s[e0]) e0 = e;
        int e1 = -1;
        for (int e = 0; e < NEXP; e++) {
            if (e == e0) continue;
            if (e1 < 0 || s[e] > s[e1]) e1 = e;
        }
        float w0 = s[e0], w1 = s[e1];
        float denom = w0 + w1 + 1e-20f;
        top_i[t * 2 + 0] = e0;
        top_i[t * 2 + 1] = e1;
        top_w[t * 2 + 0] = w0 / denom;
        top_w[t * 2 + 1] = w1 / denom;
    }
}

// ---------------- routing bookkeeping ----------------
__global__ void assign_kernel(const int* __restrict__ top_i, int* __restrict__ cnt,
                              int* __restrict__ rnk) {
    int j = blockIdx.x * blockDim.x + threadIdx.x;
    if (j < NROWS) rnk[j] = atomicAdd(&cnt[top_i[j]], 1);
}

__global__ void scan_kernel(const int* __restrict__ cnt, int* __restrict__ offs2,
                            int* __restrict__ cnt2) {
    if (threadIdx.x == 0) {
        int o = 0;
        for (int e = 0; e < NEXP; e++) { offs2[e] = o; cnt2[e] = cnt[e]; o += cnt[e]; }
        offs2[8] = NROWS;          cnt2[8] = NTOK;
        offs2[9] = NROWS + NTOK;   cnt2[9] = NTOK;
        offs2[10] = TROWS;
    }
}

__global__ void fill_kernel(const int* __restrict__ top_i, const float* __restrict__ top_w,
                            const int* __restrict__ rnk, const int* __restrict__ offs2,
                            int* __restrict__ tok_of_row, float* __restrict__ w_of_row) {
    int j = blockIdx.x * blockDim.x + threadIdx.x;
    if (j < NROWS) {
        int row = offs2[top_i[j]] + rnk[j];
        tok_of_row[row] = j;  // token = j>>1
        w_of_row[row] = top_w[j];
    }
}

__global__ void fill_shared(int* __restrict__ tok_of_row, float* __restrict__ w_of_row) {
    int j = blockIdx.x * blockDim.x + threadIdx.x;  // 0..8191
    int row = NROWS + j;
    tok_of_row[row] = (j & (NTOK - 1)) << 1;  // token = j mod 4096
    w_of_row[row] = 1.0f;
}

// ============ GEMM 1: act = silu(x@Wg)*(x@Wu) ==============================
// 256 thr / 4 waves (2x2), tile 128Mx128N over BOTH Wg and Wu (32 MFMA per
// barrier window), BK=32, fragment-ordered LDS (conflict-free), 2-phase
// prefetch double-buffer, one __syncthreads per K-step.  LDS 48KB.
__global__ __launch_bounds__(256, 2) void gemm_gu(
    const ushort_t* __restrict__ xb, const ushort_t* __restrict__ WgT,
    const ushort_t* __restrict__ WuT, ushort_t* __restrict__ act,
    const int* __restrict__ tok_of_row, const int* __restrict__ offs2,
    const int* __restrict__ cnt2) {
    int bx, by, bz;
    swz3(bx, by, bz);
    int e = bz;
    int mcnt = cnt2[e];
    int m0 = by * 128;
    if (m0 >= mcnt) return;
    int base = offs2[e];
    int n0 = bx * 128;
    const ushort_t* Bg = WgT + (size_t)e * INTER * HIDDEN;
    const ushort_t* Bu = WuT + (size_t)e * INTER * HIDDEN;

    __shared__ short As[2][8 * 512];
    __shared__ short Bgs[2][8 * 512];
    __shared__ short Bus[2][8 * 512];

    int tid = threadIdx.x;
    int wave = tid >> 6, lane = tid & 63;
    int wr = wave >> 1, wc = wave & 1;  // 2x2 waves, each 64x64
    int lr = lane & 15;
    int kq = (lane >> 4) * 8;

    // staging sources (fragment-ordered: lane -> row lr of subtile, chunk kq)
    int ar0 = 32 * wave + lr, ar1 = ar0 + 16;
    int rr0 = base + imin(m0 + ar0, mcnt - 1);
    int rr1 = base + imin(m0 + ar1, mcnt - 1);
    const ushort_t* srcA0 = xb + (size_t)(tok_of_row[rr0] >> 1) * HIDDEN + kq;
    const ushort_t* srcA1 = xb + (size_t)(tok_of_row[rr1] >> 1) * HIDDEN + kq;
    const ushort_t* srcBg0 = Bg + (size_t)(n0 + 32 * wave + lr) * HIDDEN + kq;
    const ushort_t* srcBg1 = srcBg0 + (size_t)16 * HIDDEN;
    const ushort_t* srcBu0 = Bu + (size_t)(n0 + 32 * wave + lr) * HIDDEN + kq;
    const ushort_t* srcBu1 = srcBu0 + (size_t)16 * HIDDEN;

    f32x4 accG[4][4] = {};
    f32x4 accU[4][4] = {};

#define STAGE_GU(buf, k0)                                                    \
    do {                                                                     \
        GLDS16(srcA0 + (k0), &As[buf][(2 * wave) * 512]);                    \
        GLDS16(srcA1 + (k0), &As[buf][(2 * wave + 1) * 512]);                \
        GLDS16(srcBg0 + (k0), &Bgs[buf][(2 * wave) * 512]);                  \
        GLDS16(srcBg1 + (k0), &Bgs[buf][(2 * wave + 1) * 512]);              \
        GLDS16(srcBu0 + (k0), &Bus[buf][(2 * wave) * 512]);                  \
        GLDS16(srcBu1 + (k0), &Bus[buf][(2 * wave + 1) * 512]);              \
    } while (0)

    STAGE_GU(0, 0);
    __syncthreads();

    const int NT = HIDDEN / 32;
    int cur = 0;
    for (int t = 0; t < NT; t++) {
        if (t + 1 < NT) STAGE_GU(cur ^ 1, (t + 1) * 32);
        short8 a[4], bg[4], bu[4];
#pragma unroll
        for (int mi = 0; mi < 4; mi++)
            a[mi] = *reinterpret_cast<const short8*>(
                &As[cur][(wr * 4 + mi) * 512 + lane * 8]);
#pragma unroll
        for (int ni = 0; ni < 4; ni++) {
            bg[ni] = *reinterpret_cast<const short8*>(
                &Bgs[cur][(wc * 4 + ni) * 512 + lane * 8]);
            bu[ni] = *reinterpret_cast<const short8*>(
                &Bus[cur][(wc * 4 + ni) * 512 + lane * 8]);
        }
#pragma unroll
        for (int mi = 0; mi < 4; mi++)
#pragma unroll
            for (int ni = 0; ni < 4; ni++) {
                accG[mi][ni] = __builtin_amdgcn_mfma_f32_16x16x32_bf16(
                    a[mi], bg[ni], accG[mi][ni], 0, 0, 0);
                accU[mi][ni] = __builtin_amdgcn_mfma_f32_16x16x32_bf16(
                    a[mi], bu[ni], accU[mi][ni], 0, 0, 0);
            }
        __syncthreads();
        cur ^= 1;
    }
#undef STAGE_GU

    // epilogue: silu(g)*u -> bf16 act (compact rows)
#pragma unroll
    for (int mi = 0; mi < 4; mi++) {
#pragma unroll
        for (int r = 0; r < 4; r++) {
            int gm = m0 + wr * 64 + mi * 16 + (lane >> 4) * 4 + r;
            if (gm < mcnt) {
#pragma unroll
                for (int ni = 0; ni < 4; ni++) {
                    int col = n0 + wc * 64 + ni * 16 + lr;
                    float g = accG[mi][ni][r], u = accU[mi][ni][r];
                    act[(size_t)(base + gm) * INTER + col] = f2bf(silu_f(g) * u);
                }
            }
        }
    }
}

// ============ GEMM 2: out += w * (act @ Wd) ================================
// 256 thr / 4 waves, tile 128Mx256N (32 MFMA per window), BK=32, dbuf.
__global__ __launch_bounds__(256, 2) void gemm_down(
    const ushort_t* __restrict__ act, const ushort_t* __restrict__ WdT,
    float* __restrict__ out, const int* __restrict__ tok_of_row,
    const float* __restrict__ w_of_row, const int* __restrict__ offs2,
    const int* __restrict__ cnt2) {
    int bx, by, bz;
    swz3(bx, by, bz);
    int e = bz;
    int mcnt = cnt2[e];
    int m0 = by * 128;
    if (m0 >= mcnt) return;
    int base = offs2[e];
    int n0 = bx * 256;
    const ushort_t* Bd = WdT + (size_t)e * HIDDEN * INTER;

    __shared__ short As[2][8 * 512];
    __shared__ short Bs[2][16 * 512];

    int tid = threadIdx.x;
    int wave = tid >> 6, lane = tid & 63;
    int wr = wave >> 1, wc = wave & 1;  // each wave: 64M x 128N
    int lr = lane & 15;
    int kq = (lane >> 4) * 8;

    // A rows compact; reads past panel end hit valid ws memory, discarded.
    const ushort_t* srcA0 = act + (size_t)(base + m0 + 32 * wave + lr) * INTER + kq;
    const ushort_t* srcA1 = srcA0 + (size_t)16 * INTER;
    const ushort_t* srcB0 = Bd + (size_t)(n0 + 64 * wave + lr) * INTER + kq;
    const ushort_t* srcB1 = srcB0 + (size_t)16 * INTER;
    const ushort_t* srcB2 = srcB0 + (size_t)32 * INTER;
    const ushort_t* srcB3 = srcB0 + (size_t)48 * INTER;

    f32x4 acc[4][8] = {};

#define STAGE_D(buf, k0)                                                     \
    do {                                                                     \
        GLDS16(srcA0 + (k0), &As[buf][(2 * wave) * 512]);                    \
        GLDS16(srcA1 + (k0), &As[buf][(2 * wave + 1) * 512]);                \
        GLDS16(srcB0 + (k0), &Bs[buf][(4 * wave) * 512]);                    \
        GLDS16(srcB1 + (k0), &Bs[buf][(4 * wave + 1) * 512]);                \
        GLDS16(srcB2 + (k0), &Bs[buf][(4 * wave + 2) * 512]);                \
        GLDS16(srcB3 + (k0), &Bs[buf][(4 * wave + 3) * 512]);                \
    } while (0)

    STAGE_D(0, 0);
    __syncthreads();

    const int NT = INTER / 32;
    int cur = 0;
    for (int t = 0; t < NT; t++) {
        if (t + 1 < NT) STAGE_D(cur ^ 1, (t + 1) * 32);
        short8 a[4], b[8];
#pragma unroll
        for (int mi = 0; mi < 4; mi++)
            a[mi] = *reinterpret_cast<const short8*>(
                &As[cur][(wr * 4 + mi) * 512 + lane * 8]);
#pragma unroll
        for (int ni = 0; ni < 8; ni++)
            b[ni] = *reinterpret_cast<const short8*>(
                &Bs[cur][(wc * 8 + ni) * 512 + lane * 8]);
#pragma unroll
        for (int mi = 0; mi < 4; mi++)
#pragma unroll
            for (int ni = 0; ni < 8; ni++)
                acc[mi][ni] = __builtin_amdgcn_mfma_f32_16x16x32_bf16(
                    a[mi], b[ni], acc[mi][ni], 0, 0, 0);
        __syncthreads();
        cur ^= 1;
    }
#undef STAGE_D

#pragma unroll
    for (int mi = 0; mi < 4; mi++) {
#pragma unroll
        for (int r = 0; r < 4; r++) {
            int gm = m0 + wr * 64 + mi * 16 + (lane >> 4) * 4 + r;
            if (gm < mcnt) {
                int tok = tok_of_row[base + gm] >> 1;
                float w = w_of_row[base + gm];
#pragma unroll
                for (int ni = 0; ni < 8; ni++) {
                    int col = n0 + wc * 128 + ni * 16 + lr;
                    atomicAdd(&out[(size_t)tok * HIDDEN + col], w * acc[mi][ni][r]);
                }
            }
        }
    }
}

extern "C" void kernel_launch(void* const* d_in, const int* in_sizes, int n_in,
                              void* d_out, int out_size, void* d_ws, size_t ws_size,
                              hipStream_t stream) {
    const float* x   = (const float*)d_in[0];
    const float* gw  = (const float*)d_in[1];
    const float* wg  = (const float*)d_in[2];
    const float* wu  = (const float*)d_in[3];
    const float* wd  = (const float*)d_in[4];
    const float* swg = (const float*)d_in[5];
    const float* swu = (const float*)d_in[6];
    const float* swd = (const float*)d_in[7];
    float* out = (float*)d_out;

    // ---- workspace layout (bf16 buffers first, 16B-aligned) ----
    const size_t XB   = (size_t)NTOK * HIDDEN;
    const size_t WPAN = (size_t)NPANEL * INTER * HIDDEN;
    const size_t ACT  = (size_t)TROWS * INTER;
    ushort_t* xb  = (ushort_t*)d_ws;
    ushort_t* wgT = xb + XB;
    ushort_t* wuT = wgT + WPAN;
    ushort_t* wdT = wuT + WPAN;
    ushort_t* act = wdT + WPAN;
    int* ib = (int*)(act + ACT);
    int* top_i      = ib;                 // NROWS
    int* rnk        = ib + NROWS;         // NROWS
    int* cnt        = ib + 2 * NROWS;     // 8
    int* offs2      = ib + 2 * NROWS + 8; // 16
    int* cnt2       = offs2 + 16;         // 16
    int* tok_of_row = cnt2 + 16;          // TROWS
    float* top_w    = (float*)(tok_of_row + TROWS);  // NROWS
    float* w_of_row = top_w + NROWS;                 // TROWS

    // ---- 1. dtype conversions (+ weight transposes to [N][K]) ----
    conv_x<<<(NTOK * HIDDEN) / (256 * 4), 256, 0, stream>>>(x, xb);
    dim3 tb(32, 8);
    tconv<<<dim3(INTER / 32, HIDDEN / 32, NEXP), tb, 0, stream>>>(
        wg, wgT, HIDDEN, INTER, (long)HIDDEN * INTER, (long)INTER * HIDDEN);
    tconv<<<dim3(INTER / 32, HIDDEN / 32, NEXP), tb, 0, stream>>>(
        wu, wuT, HIDDEN, INTER, (long)HIDDEN * INTER, (long)INTER * HIDDEN);
    tconv<<<dim3(SINTER / 32, HIDDEN / 32, 1), tb, 0, stream>>>(
        swg, wgT + (size_t)8 * INTER * HIDDEN, HIDDEN, SINTER, 0, 0);
    tconv<<<dim3(SINTER / 32, HIDDEN / 32, 1), tb, 0, stream>>>(
        swu, wuT + (size_t)8 * INTER * HIDDEN, HIDDEN, SINTER, 0, 0);
    tconv<<<dim3(HIDDEN / 32, INTER / 32, NEXP), tb, 0, stream>>>(
        wd, wdT, INTER, HIDDEN, (long)INTER * HIDDEN, (long)HIDDEN * INTER);
    tconv<<<dim3(HIDDEN / 32, INTER / 32, 2), tb, 0, stream>>>(
        swd, wdT + (size_t)8 * HIDDEN * INTER, INTER, HIDDEN,
        (long)INTER * HIDDEN, (long)HIDDEN * INTER);

    // ---- 2. gate + routing ----
    gate_kernel<<<NTOK, 64, 0, stream>>>(x, gw, top_i, top_w);
    hipMemsetAsync(cnt, 0, 8 * sizeof(int), stream);
    assign_kernel<<<NROWS / 256, 256, 0, stream>>>(top_i, cnt, rnk);
    scan_kernel<<<1, 1, 0, stream>>>(cnt, offs2, cnt2);
    fill_kernel<<<NROWS / 256, 256, 0, stream>>>(top_i, top_w, rnk, offs2,
                                                 tok_of_row, w_of_row);
    fill_shared<<<NROWS / 256, 256, 0, stream>>>(tok_of_row, w_of_row);

    // ---- 3. grouped SwiGLU GEMMs (routed + shared unified, 10 panels) ----
    gemm_gu<<<dim3(INTER / 128, NROWS / 128, NPANEL), 256, 0, stream>>>(
        xb, wgT, wuT, act, tok_of_row, offs2, cnt2);
    hipMemsetAsync(out, 0, (size_t)out_size * sizeof(float), stream);
    gemm_down<<<dim3(HIDDEN / 256, NROWS / 128, NPANEL), 256, 0, stream>>>(
        act, wdT, out, tok_of_row, w_of_row, offs2, cnt2);
}

// Round 6
// 573.265 us; speedup vs baseline: 1.1177x; 1.1177x over previous
//
#include <hip/hip_runtime.h>
#include <hip/hip_bf16.h>
#include <math.h>

#define HIDDEN 1024
#define NEXP 8
#define TOPK 2
#define INTER 1408
#define SINTER 2816
#define NTOK 4096
#define NROWS (NTOK * TOPK) /* 8192 routed rows */
#define NPANEL 10           /* 8 routed + 2 shared halves */
#define TROWS 16384         /* NROWS + 2*NTOK */

typedef unsigned short ushort_t;
typedef __attribute__((ext_vector_type(8))) short short8;
typedef __attribute__((ext_vector_type(4))) float f32x4;

__device__ __forceinline__ ushort_t f2bf(float f) {
    unsigned int b = __float_as_uint(f);
    unsigned int r = (b + 0x7FFFu + ((b >> 16) & 1u)) >> 16;
    return (ushort_t)r;
}
__device__ __forceinline__ float silu_f(float g) {
    return g * (1.0f / (1.0f + __expf(-g)));
}
__device__ __forceinline__ int imin(int a, int b) { return a < b ? a : b; }

#define GLDS16(gp, lp) __builtin_amdgcn_global_load_lds(                     \
    (const __attribute__((address_space(1))) void*)(gp),                     \
    (__attribute__((address_space(3))) void*)(lp), 16, 0, 0)

// bijective XCD-chunked block swizzle (total blocks % 8 == 0).
// HW block id -> logical tile: XCD c handles a contiguous logical range.
__device__ __forceinline__ void swz3(int& bx, int& by, int& bz) {
    int nb = gridDim.x, mb = gridDim.y;
    int total = nb * mb * gridDim.z;
    int orig = (blockIdx.z * mb + blockIdx.y) * nb + blockIdx.x;
    int cpx = total >> 3;
    int w = (orig & 7) * cpx + (orig >> 3);
    bz = w / (nb * mb);
    int rem = w - bz * (nb * mb);
    by = rem / nb;
    bx = rem - by * nb;
}

// ---------------- fp32 -> bf16 elementwise (x) ----------------
__global__ void conv_x(const float* __restrict__ src, ushort_t* __restrict__ dst) {
    int i = (blockIdx.x * 256 + threadIdx.x) * 4;
    float4 v = *reinterpret_cast<const float4*>(&src[i]);
    union { ushort_t h[4]; unsigned long long ll; } p;
    p.h[0] = f2bf(v.x); p.h[1] = f2bf(v.y); p.h[2] = f2bf(v.z); p.h[3] = f2bf(v.w);
    *reinterpret_cast<unsigned long long*>(&dst[i]) = p.ll;
}

// ---- fp32 [R][C] -> bf16 [C][R] transpose-convert -------------------------
__global__ void tconv(const float* __restrict__ src, ushort_t* __restrict__ dst,
                      int R, int C, long sstride, long dstride) {
    src += (size_t)blockIdx.z * sstride;
    dst += (size_t)blockIdx.z * dstride;
    __shared__ float tile[32][33];
    int ct = blockIdx.x * 32, rt = blockIdx.y * 32;
    int tx = threadIdx.x, ty = threadIdx.y;  // 32 x 8
#pragma unroll
    for (int i = 0; i < 4; i++)
        tile[ty + 8 * i][tx] = src[(size_t)(rt + ty + 8 * i) * C + ct + tx];
    __syncthreads();
#pragma unroll
    for (int i = 0; i < 4; i++)
        dst[(size_t)(ct + ty + 8 * i) * R + rt + tx] = f2bf(tile[tx][ty + 8 * i]);
}

// ---------------- gate: logits -> softmax -> top2 -> normalized weights ----
__global__ void gate_kernel(const float* __restrict__ x, const float* __restrict__ gw,
                            int* __restrict__ top_i, float* __restrict__ top_w) {
    int t = blockIdx.x;
    int lane = threadIdx.x;
    const float* xr = x + (size_t)t * HIDDEN;
    float acc[NEXP];
#pragma unroll
    for (int e = 0; e < NEXP; e++) acc[e] = 0.f;
    for (int j = 0; j < HIDDEN / 64; j++) {
        float xv = xr[lane + 64 * j];
#pragma unroll
        for (int e = 0; e < NEXP; e++)
            acc[e] = fmaf(xv, gw[e * HIDDEN + lane + 64 * j], acc[e]);
    }
#pragma unroll
    for (int e = 0; e < NEXP; e++) {
        float v = acc[e];
        for (int off = 32; off > 0; off >>= 1) v += __shfl_xor(v, off, 64);
        acc[e] = v;
    }
    if (lane == 0) {
        float mx = acc[0];
        for (int e = 1; e < NEXP; e++) mx = fmaxf(mx, acc[e]);
        float s[NEXP];
        float sum = 0.f;
        for (int e = 0; e < NEXP; e++) { s[e] = __expf(acc[e] - mx); sum += s[e]; }
        float inv = 1.0f / sum;
        for (int e = 0; e < NEXP; e++) s[e] *= inv;
        int e0 = 0;
        for (int e = 1; e < NEXP; e++) if (s[e] > s[e0]) e0 = e;
        int e1 = -1;
        for (int e = 0; e < NEXP; e++) {
            if (e == e0) continue;
            if (e1 < 0 || s[e] > s[e1]) e1 = e;
        }
        float w0 = s[e0], w1 = s[e1];
        float denom = w0 + w1 + 1e-20f;
        top_i[t * 2 + 0] = e0;
        top_i[t * 2 + 1] = e1;
        top_w[t * 2 + 0] = w0 / denom;
        top_w[t * 2 + 1] = w1 / denom;
    }
}

// ---------------- routing bookkeeping ----------------
__global__ void assign_kernel(const int* __restrict__ top_i, int* __restrict__ cnt,
                              int* __restrict__ rnk) {
    int j = blockIdx.x * blockDim.x + threadIdx.x;
    if (j < NROWS) rnk[j] = atomicAdd(&cnt[top_i[j]], 1);
}

__global__ void scan_kernel(const int* __restrict__ cnt, int* __restrict__ offs2,
                            int* __restrict__ cnt2) {
    if (threadIdx.x == 0) {
        int o = 0;
        for (int e = 0; e < NEXP; e++) { offs2[e] = o; cnt2[e] = cnt[e]; o += cnt[e]; }
        offs2[8] = NROWS;          cnt2[8] = NTOK;
        offs2[9] = NROWS + NTOK;   cnt2[9] = NTOK;
        offs2[10] = TROWS;
    }
}

__global__ void fill_kernel(const int* __restrict__ top_i, const float* __restrict__ top_w,
                            const int* __restrict__ rnk, const int* __restrict__ offs2,
                            int* __restrict__ tok_of_row, float* __restrict__ w_of_row) {
    int j = blockIdx.x * blockDim.x + threadIdx.x;
    if (j < NROWS) {
        int row = offs2[top_i[j]] + rnk[j];
        tok_of_row[row] = j;  // token = j>>1
        w_of_row[row] = top_w[j];
    }
}

__global__ void fill_shared(int* __restrict__ tok_of_row, float* __restrict__ w_of_row) {
    int j = blockIdx.x * blockDim.x + threadIdx.x;  // 0..8191
    int row = NROWS + j;
    tok_of_row[row] = (j & (NTOK - 1)) << 1;  // token = j mod 4096
    w_of_row[row] = 1.0f;
}

// ============ GEMM 1: act = silu(x@Wg)*(x@Wu) ==============================
// R2 structure (proven): 256 thr / 4 waves (2x2), tile 128Mx128N over BOTH
// Wg and Wu (32 MFMA per barrier window), BK=32, single-buffer 24KB LDS,
// stage -> sync -> frag-read -> MFMA -> sync.
// NEW vs R2: fragment-ordered LDS (lane l <-> (row=l&15, chunk=l>>4), so
// ds_read_b128 is identity lane*16 -> ZERO bank conflicts), XCD swizzle.
__global__ __launch_bounds__(256, 2) void gemm_gu(
    const ushort_t* __restrict__ xb, const ushort_t* __restrict__ WgT,
    const ushort_t* __restrict__ WuT, ushort_t* __restrict__ act,
    const int* __restrict__ tok_of_row, const int* __restrict__ offs2,
    const int* __restrict__ cnt2) {
    int bx, by, bz;
    swz3(bx, by, bz);
    int e = bz;
    int mcnt = cnt2[e];
    int m0 = by * 128;
    if (m0 >= mcnt) return;
    int base = offs2[e];
    int n0 = bx * 128;
    const ushort_t* Bg = WgT + (size_t)e * INTER * HIDDEN;
    const ushort_t* Bu = WuT + (size_t)e * INTER * HIDDEN;

    __shared__ short As[8 * 512];
    __shared__ short Bgs[8 * 512];
    __shared__ short Bus[8 * 512];

    int tid = threadIdx.x;
    int wave = tid >> 6, lane = tid & 63;
    int wr = wave >> 1, wc = wave & 1;  // 2x2 waves, each 64x64
    int lr = lane & 15;
    int kq = (lane >> 4) * 8;  // k-chunk of this lane (8 bf16 = 16B)

    // staging sources: wave stages subtiles {2w,2w+1} of A and of each B
    int r0 = m0 + 32 * wave + lr, r1 = r0 + 16;
    int rr0 = base + imin(r0, mcnt - 1);
    int rr1 = base + imin(r1, mcnt - 1);
    const ushort_t* srcA0 = xb + (size_t)(tok_of_row[rr0] >> 1) * HIDDEN + kq;
    const ushort_t* srcA1 = xb + (size_t)(tok_of_row[rr1] >> 1) * HIDDEN + kq;
    const ushort_t* srcBg0 = Bg + (size_t)(n0 + 32 * wave + lr) * HIDDEN + kq;
    const ushort_t* srcBg1 = srcBg0 + (size_t)16 * HIDDEN;
    const ushort_t* srcBu0 = Bu + (size_t)(n0 + 32 * wave + lr) * HIDDEN + kq;
    const ushort_t* srcBu1 = srcBu0 + (size_t)16 * HIDDEN;

    f32x4 accG[4][4] = {};
    f32x4 accU[4][4] = {};

    for (int k0 = 0; k0 < HIDDEN; k0 += 32) {
        GLDS16(srcA0 + k0, &As[(2 * wave) * 512]);
        GLDS16(srcA1 + k0, &As[(2 * wave + 1) * 512]);
        GLDS16(srcBg0 + k0, &Bgs[(2 * wave) * 512]);
        GLDS16(srcBg1 + k0, &Bgs[(2 * wave + 1) * 512]);
        GLDS16(srcBu0 + k0, &Bus[(2 * wave) * 512]);
        GLDS16(srcBu1 + k0, &Bus[(2 * wave + 1) * 512]);
        __syncthreads();
        short8 a[4], bg[4], bu[4];
#pragma unroll
        for (int mi = 0; mi < 4; mi++)
            a[mi] = *reinterpret_cast<const short8*>(
                &As[(wr * 4 + mi) * 512 + lane * 8]);
#pragma unroll
        for (int ni = 0; ni < 4; ni++) {
            bg[ni] = *reinterpret_cast<const short8*>(
                &Bgs[(wc * 4 + ni) * 512 + lane * 8]);
            bu[ni] = *reinterpret_cast<const short8*>(
                &Bus[(wc * 4 + ni) * 512 + lane * 8]);
        }
#pragma unroll
        for (int mi = 0; mi < 4; mi++)
#pragma unroll
            for (int ni = 0; ni < 4; ni++) {
                accG[mi][ni] = __builtin_amdgcn_mfma_f32_16x16x32_bf16(
                    a[mi], bg[ni], accG[mi][ni], 0, 0, 0);
                accU[mi][ni] = __builtin_amdgcn_mfma_f32_16x16x32_bf16(
                    a[mi], bu[ni], accU[mi][ni], 0, 0, 0);
            }
        __syncthreads();
    }

    // epilogue: silu(g)*u -> bf16 act (compact rows)
#pragma unroll
    for (int mi = 0; mi < 4; mi++) {
#pragma unroll
        for (int r = 0; r < 4; r++) {
            int gm = m0 + wr * 64 + mi * 16 + (lane >> 4) * 4 + r;
            if (gm < mcnt) {
#pragma unroll
                for (int ni = 0; ni < 4; ni++) {
                    int col = n0 + wc * 64 + ni * 16 + lr;
                    float g = accG[mi][ni][r], u = accU[mi][ni][r];
                    act[(size_t)(base + gm) * INTER + col] = f2bf(silu_f(g) * u);
                }
            }
        }
    }
}

// ============ GEMM 2: out += w * (act @ Wd) ================================
// Same proven structure, tile 128Mx256N (32 MFMA per window), single-buf
// 24KB LDS, fragment-ordered, 2 barriers per K-step, XCD swizzle.
__global__ __launch_bounds__(256, 2) void gemm_down(
    const ushort_t* __restrict__ act, const ushort_t* __restrict__ WdT,
    float* __restrict__ out, const int* __restrict__ tok_of_row,
    const float* __restrict__ w_of_row, const int* __restrict__ offs2,
    const int* __restrict__ cnt2) {
    int bx, by, bz;
    swz3(bx, by, bz);
    int e = bz;
    int mcnt = cnt2[e];
    int m0 = by * 128;
    if (m0 >= mcnt) return;
    int base = offs2[e];
    int n0 = bx * 256;
    const ushort_t* Bd = WdT + (size_t)e * HIDDEN * INTER;

    __shared__ short As[8 * 512];
    __shared__ short Bs[16 * 512];

    int tid = threadIdx.x;
    int wave = tid >> 6, lane = tid & 63;
    int wr = wave >> 1, wc = wave & 1;  // each wave: 64M x 128N
    int lr = lane & 15;
    int kq = (lane >> 4) * 8;

    // A rows compact; max staged row = base+m0+127 <= TROWS-1 (exact fit for
    // last panel); spill rows belong to next panel, outputs discarded.
    const ushort_t* srcA0 = act + (size_t)(base + m0 + 32 * wave + lr) * INTER + kq;
    const ushort_t* srcA1 = srcA0 + (size_t)16 * INTER;
    const ushort_t* srcB0 = Bd + (size_t)(n0 + 64 * wave + lr) * INTER + kq;
    const ushort_t* srcB1 = srcB0 + (size_t)16 * INTER;
    const ushort_t* srcB2 = srcB0 + (size_t)32 * INTER;
    const ushort_t* srcB3 = srcB0 + (size_t)48 * INTER;

    f32x4 acc[4][8] = {};

    for (int k0 = 0; k0 < INTER; k0 += 32) {
        GLDS16(srcA0 + k0, &As[(2 * wave) * 512]);
        GLDS16(srcA1 + k0, &As[(2 * wave + 1) * 512]);
        GLDS16(srcB0 + k0, &Bs[(4 * wave) * 512]);
        GLDS16(srcB1 + k0, &Bs[(4 * wave + 1) * 512]);
        GLDS16(srcB2 + k0, &Bs[(4 * wave + 2) * 512]);
        GLDS16(srcB3 + k0, &Bs[(4 * wave + 3) * 512]);
        __syncthreads();
        short8 a[4], b[8];
#pragma unroll
        for (int mi = 0; mi < 4; mi++)
            a[mi] = *reinterpret_cast<const short8*>(
                &As[(wr * 4 + mi) * 512 + lane * 8]);
#pragma unroll
        for (int ni = 0; ni < 8; ni++)
            b[ni] = *reinterpret_cast<const short8*>(
                &Bs[(wc * 8 + ni) * 512 + lane * 8]);
#pragma unroll
        for (int mi = 0; mi < 4; mi++)
#pragma unroll
            for (int ni = 0; ni < 8; ni++)
                acc[mi][ni] = __builtin_amdgcn_mfma_f32_16x16x32_bf16(
                    a[mi], b[ni], acc[mi][ni], 0, 0, 0);
        __syncthreads();
    }

#pragma unroll
    for (int mi = 0; mi < 4; mi++) {
#pragma unroll
        for (int r = 0; r < 4; r++) {
            int gm = m0 + wr * 64 + mi * 16 + (lane >> 4) * 4 + r;
            if (gm < mcnt) {
                int tok = tok_of_row[base + gm] >> 1;
                float w = w_of_row[base + gm];
#pragma unroll
                for (int ni = 0; ni < 8; ni++) {
                    int col = n0 + wc * 128 + ni * 16 + lr;
                    atomicAdd(&out[(size_t)tok * HIDDEN + col], w * acc[mi][ni][r]);
                }
            }
        }
    }
}

extern "C" void kernel_launch(void* const* d_in, const int* in_sizes, int n_in,
                              void* d_out, int out_size, void* d_ws, size_t ws_size,
                              hipStream_t stream) {
    const float* x   = (const float*)d_in[0];
    const float* gw  = (const float*)d_in[1];
    const float* wg  = (const float*)d_in[2];
    const float* wu  = (const float*)d_in[3];
    const float* wd  = (const float*)d_in[4];
    const float* swg = (const float*)d_in[5];
    const float* swu = (const float*)d_in[6];
    const float* swd = (const float*)d_in[7];
    float* out = (float*)d_out;

    // ---- workspace layout (bf16 buffers first, 16B-aligned) ----
    const size_t XB   = (size_t)NTOK * HIDDEN;
    const size_t WPAN = (size_t)NPANEL * INTER * HIDDEN;
    const size_t ACT  = (size_t)TROWS * INTER;
    ushort_t* xb  = (ushort_t*)d_ws;
    ushort_t* wgT = xb + XB;
    ushort_t* wuT = wgT + WPAN;
    ushort_t* wdT = wuT + WPAN;
    ushort_t* act = wdT + WPAN;
    int* ib = (int*)(act + ACT);
    int* top_i      = ib;                 // NROWS
    int* rnk        = ib + NROWS;         // NROWS
    int* cnt        = ib + 2 * NROWS;     // 8
    int* offs2      = ib + 2 * NROWS + 8; // 16
    int* cnt2       = offs2 + 16;         // 16
    int* tok_of_row = cnt2 + 16;          // TROWS
    float* top_w    = (float*)(tok_of_row + TROWS);  // NROWS
    float* w_of_row = top_w + NROWS;                 // TROWS

    // ---- 1. dtype conversions (+ weight transposes to [N][K]) ----
    conv_x<<<(NTOK * HIDDEN) / (256 * 4), 256, 0, stream>>>(x, xb);
    dim3 tb(32, 8);
    tconv<<<dim3(INTER / 32, HIDDEN / 32, NEXP), tb, 0, stream>>>(
        wg, wgT, HIDDEN, INTER, (long)HIDDEN * INTER, (long)INTER * HIDDEN);
    tconv<<<dim3(INTER / 32, HIDDEN / 32, NEXP), tb, 0, stream>>>(
        wu, wuT, HIDDEN, INTER, (long)HIDDEN * INTER, (long)INTER * HIDDEN);
    tconv<<<dim3(SINTER / 32, HIDDEN / 32, 1), tb, 0, stream>>>(
        swg, wgT + (size_t)8 * INTER * HIDDEN, HIDDEN, SINTER, 0, 0);
    tconv<<<dim3(SINTER / 32, HIDDEN / 32, 1), tb, 0, stream>>>(
        swu, wuT + (size_t)8 * INTER * HIDDEN, HIDDEN, SINTER, 0, 0);
    tconv<<<dim3(HIDDEN / 32, INTER / 32, NEXP), tb, 0, stream>>>(
        wd, wdT, INTER, HIDDEN, (long)INTER * HIDDEN, (long)HIDDEN * INTER);
    tconv<<<dim3(HIDDEN / 32, INTER / 32, 2), tb, 0, stream>>>(
        swd, wdT + (size_t)8 * HIDDEN * INTER, INTER, HIDDEN,
        (long)INTER * HIDDEN, (long)HIDDEN * INTER);

    // ---- 2. gate + routing ----
    gate_kernel<<<NTOK, 64, 0, stream>>>(x, gw, top_i, top_w);
    hipMemsetAsync(cnt, 0, 8 * sizeof(int), stream);
    assign_kernel<<<NROWS / 256, 256, 0, stream>>>(top_i, cnt, rnk);
    scan_kernel<<<1, 1, 0, stream>>>(cnt, offs2, cnt2);
    fill_kernel<<<NROWS / 256, 256, 0, stream>>>(top_i, top_w, rnk, offs2,
                                                 tok_of_row, w_of_row);
    fill_shared<<<NROWS / 256, 256, 0, stream>>>(tok_of_row, w_of_row);

    // ---- 3. grouped SwiGLU GEMMs (routed + shared unified, 10 panels) ----
    gemm_gu<<<dim3(INTER / 128, NROWS / 128, NPANEL), 256, 0, stream>>>(
        xb, wgT, wuT, act, tok_of_row, offs2, cnt2);
    hipMemsetAsync(out, 0, (size_t)out_size * sizeof(float), stream);
    gemm_down<<<dim3(HIDDEN / 256, NROWS / 128, NPANEL), 256, 0, stream>>>(
        act, wdT, out, tok_of_row, w_of_row, offs2, cnt2);
}

// Round 7
// 443.973 us; speedup vs baseline: 1.4432x; 1.2912x over previous
//
#include <hip/hip_runtime.h>
#include <hip/hip_bf16.h>
#include <math.h>

#define HIDDEN 1024
#define NEXP 8
#define TOPK 2
#define INTER 1408
#define SINTER 2816
#define NTOK 4096
#define NROWS (NTOK * TOPK) /* 8192 routed rows */
#define NPANEL 10           /* 8 routed + 2 shared halves */
#define TROWS 16384         /* NROWS + 2*NTOK */
#define MAXT 136            /* max (panel, m-block) tasks: <=71 routed + 64 shared */

typedef unsigned short ushort_t;
typedef __attribute__((ext_vector_type(8))) short short8;
typedef __attribute__((ext_vector_type(4))) float f32x4;

__device__ __forceinline__ ushort_t f2bf(float f) {
    unsigned int b = __float_as_uint(f);
    unsigned int r = (b + 0x7FFFu + ((b >> 16) & 1u)) >> 16;
    return (ushort_t)r;
}
__device__ __forceinline__ float silu_f(float g) {
    return g * (1.0f / (1.0f + __expf(-g)));
}
__device__ __forceinline__ int imin(int a, int b) { return a < b ? a : b; }

#define GLDS16(gp, lp) __builtin_amdgcn_global_load_lds(                     \
    (const __attribute__((address_space(1))) void*)(gp),                     \
    (__attribute__((address_space(3))) void*)(lp), 16, 0, 0)

// ---------------- fp32 -> bf16 elementwise (x) ----------------
__global__ void conv_x(const float* __restrict__ src, ushort_t* __restrict__ dst) {
    int i = (blockIdx.x * 256 + threadIdx.x) * 4;
    float4 v = *reinterpret_cast<const float4*>(&src[i]);
    union { ushort_t h[4]; unsigned long long ll; } p;
    p.h[0] = f2bf(v.x); p.h[1] = f2bf(v.y); p.h[2] = f2bf(v.z); p.h[3] = f2bf(v.w);
    *reinterpret_cast<unsigned long long*>(&dst[i]) = p.ll;
}

// ---- fp32 [R][C] -> bf16 [C][R] transpose-convert -------------------------
__global__ void tconv(const float* __restrict__ src, ushort_t* __restrict__ dst,
                      int R, int C, long sstride, long dstride) {
    src += (size_t)blockIdx.z * sstride;
    dst += (size_t)blockIdx.z * dstride;
    __shared__ float tile[32][33];
    int ct = blockIdx.x * 32, rt = blockIdx.y * 32;
    int tx = threadIdx.x, ty = threadIdx.y;  // 32 x 8
#pragma unroll
    for (int i = 0; i < 4; i++)
        tile[ty + 8 * i][tx] = src[(size_t)(rt + ty + 8 * i) * C + ct + tx];
    __syncthreads();
#pragma unroll
    for (int i = 0; i < 4; i++)
        dst[(size_t)(ct + ty + 8 * i) * R + rt + tx] = f2bf(tile[tx][ty + 8 * i]);
}

// ---------------- gate: logits -> softmax -> top2 -> normalized weights ----
__global__ void gate_kernel(const float* __restrict__ x, const float* __restrict__ gw,
                            int* __restrict__ top_i, float* __restrict__ top_w) {
    int t = blockIdx.x;
    int lane = threadIdx.x;
    const float* xr = x + (size_t)t * HIDDEN;
    float acc[NEXP];
#pragma unroll
    for (int e = 0; e < NEXP; e++) acc[e] = 0.f;
    for (int j = 0; j < HIDDEN / 64; j++) {
        float xv = xr[lane + 64 * j];
#pragma unroll
        for (int e = 0; e < NEXP; e++)
            acc[e] = fmaf(xv, gw[e * HIDDEN + lane + 64 * j], acc[e]);
    }
#pragma unroll
    for (int e = 0; e < NEXP; e++) {
        float v = acc[e];
        for (int off = 32; off > 0; off >>= 1) v += __shfl_xor(v, off, 64);
        acc[e] = v;
    }
    if (lane == 0) {
        float mx = acc[0];
        for (int e = 1; e < NEXP; e++) mx = fmaxf(mx, acc[e]);
        float s[NEXP];
        float sum = 0.f;
        for (int e = 0; e < NEXP; e++) { s[e] = __expf(acc[e] - mx); sum += s[e]; }
        float inv = 1.0f / sum;
        for (int e = 0; e < NEXP; e++) s[e] *= inv;
        int e0 = 0;
        for (int e = 1; e < NEXP; e++) if (s[e] > s[e0]) e0 = e;
        int e1 = -1;
        for (int e = 0; e < NEXP; e++) {
            if (e == e0) continue;
            if (e1 < 0 || s[e] > s[e1]) e1 = e;
        }
        float w0 = s[e0], w1 = s[e1];
        float denom = w0 + w1 + 1e-20f;
        top_i[t * 2 + 0] = e0;
        top_i[t * 2 + 1] = e1;
        top_w[t * 2 + 0] = w0 / denom;
        top_w[t * 2 + 1] = w1 / denom;
    }
}

// ---------------- routing bookkeeping ----------------
__global__ void assign_kernel(const int* __restrict__ top_i, int* __restrict__ cnt,
                              int* __restrict__ rnk) {
    int j = blockIdx.x * blockDim.x + threadIdx.x;
    if (j < NROWS) rnk[j] = atomicAdd(&cnt[top_i[j]], 1);
}

// builds offsets AND the dense (panel, m-block) task table
__global__ void scan_kernel(const int* __restrict__ cnt, int* __restrict__ offs2,
                            int* __restrict__ cnt2, int* __restrict__ task_pm) {
    if (threadIdx.x == 0) {
        int o = 0;
        for (int e = 0; e < NEXP; e++) { offs2[e] = o; cnt2[e] = cnt[e]; o += cnt[e]; }
        offs2[8] = NROWS;          cnt2[8] = NTOK;
        offs2[9] = NROWS + NTOK;   cnt2[9] = NTOK;
        offs2[10] = TROWS;
        int t = 0;
        for (int e = 0; e < NPANEL; e++)
            for (int m0 = 0; m0 < cnt2[e]; m0 += 128)
                task_pm[t++] = (e << 16) | (m0 >> 7);
        for (; t < MAXT; t++) task_pm[t] = -1;
    }
}

__global__ void fill_kernel(const int* __restrict__ top_i, const float* __restrict__ top_w,
                            const int* __restrict__ rnk, const int* __restrict__ offs2,
                            int* __restrict__ tok_of_row, float* __restrict__ w_of_row) {
    int j = blockIdx.x * blockDim.x + threadIdx.x;
    if (j < NROWS) {
        int row = offs2[top_i[j]] + rnk[j];
        tok_of_row[row] = j;  // token = j>>1
        w_of_row[row] = top_w[j];
    }
}

__global__ void fill_shared(int* __restrict__ tok_of_row, float* __restrict__ w_of_row) {
    int j = blockIdx.x * blockDim.x + threadIdx.x;  // 0..8191
    int row = NROWS + j;
    tok_of_row[row] = (j & (NTOK - 1)) << 1;  // token = j mod 4096
    w_of_row[row] = 1.0f;
}

// ============ GEMM 1: act = silu(x@Wg)*(x@Wu) ==============================
// 256 thr / 4 waves (2x2), tile 128Mx128N over BOTH Wg and Wu (32 MFMA per
// barrier window), BK=32, single-buffer 24KB LDS, fragment-ordered
// (conflict-free) LDS, dense task-table dispatch, NO swizzle.
__global__ __launch_bounds__(256, 2) void gemm_gu(
    const ushort_t* __restrict__ xb, const ushort_t* __restrict__ WgT,
    const ushort_t* __restrict__ WuT, ushort_t* __restrict__ act,
    const int* __restrict__ tok_of_row, const int* __restrict__ offs2,
    const int* __restrict__ cnt2, const int* __restrict__ task_pm) {
    int tk = task_pm[blockIdx.y];
    if (tk < 0) return;
    int e = tk >> 16;
    int m0 = (tk & 0xffff) << 7;
    int bx = blockIdx.x;
    int mcnt = cnt2[e];
    int base = offs2[e];
    int n0 = bx * 128;
    const ushort_t* Bg = WgT + (size_t)e * INTER * HIDDEN;
    const ushort_t* Bu = WuT + (size_t)e * INTER * HIDDEN;

    __shared__ short As[8 * 512];
    __shared__ short Bgs[8 * 512];
    __shared__ short Bus[8 * 512];

    int tid = threadIdx.x;
    int wave = tid >> 6, lane = tid & 63;
    int wr = wave >> 1, wc = wave & 1;  // 2x2 waves, each 64x64
    int lr = lane & 15;
    int kq = (lane >> 4) * 8;  // k-chunk of this lane (8 bf16 = 16B)

    // staging sources: wave stages subtiles {2w,2w+1} of A and of each B
    int r0 = m0 + 32 * wave + lr, r1 = r0 + 16;
    int rr0 = base + imin(r0, mcnt - 1);
    int rr1 = base + imin(r1, mcnt - 1);
    const ushort_t* srcA0 = xb + (size_t)(tok_of_row[rr0] >> 1) * HIDDEN + kq;
    const ushort_t* srcA1 = xb + (size_t)(tok_of_row[rr1] >> 1) * HIDDEN + kq;
    const ushort_t* srcBg0 = Bg + (size_t)(n0 + 32 * wave + lr) * HIDDEN + kq;
    const ushort_t* srcBg1 = srcBg0 + (size_t)16 * HIDDEN;
    const ushort_t* srcBu0 = Bu + (size_t)(n0 + 32 * wave + lr) * HIDDEN + kq;
    const ushort_t* srcBu1 = srcBu0 + (size_t)16 * HIDDEN;

    f32x4 accG[4][4] = {};
    f32x4 accU[4][4] = {};

    for (int k0 = 0; k0 < HIDDEN; k0 += 32) {
        GLDS16(srcA0 + k0, &As[(2 * wave) * 512]);
        GLDS16(srcA1 + k0, &As[(2 * wave + 1) * 512]);
        GLDS16(srcBg0 + k0, &Bgs[(2 * wave) * 512]);
        GLDS16(srcBg1 + k0, &Bgs[(2 * wave + 1) * 512]);
        GLDS16(srcBu0 + k0, &Bus[(2 * wave) * 512]);
        GLDS16(srcBu1 + k0, &Bus[(2 * wave + 1) * 512]);
        __syncthreads();
        short8 a[4], bg[4], bu[4];
#pragma unroll
        for (int mi = 0; mi < 4; mi++)
            a[mi] = *reinterpret_cast<const short8*>(
                &As[(wr * 4 + mi) * 512 + lane * 8]);
#pragma unroll
        for (int ni = 0; ni < 4; ni++) {
            bg[ni] = *reinterpret_cast<const short8*>(
                &Bgs[(wc * 4 + ni) * 512 + lane * 8]);
            bu[ni] = *reinterpret_cast<const short8*>(
                &Bus[(wc * 4 + ni) * 512 + lane * 8]);
        }
#pragma unroll
        for (int mi = 0; mi < 4; mi++)
#pragma unroll
            for (int ni = 0; ni < 4; ni++) {
                accG[mi][ni] = __builtin_amdgcn_mfma_f32_16x16x32_bf16(
                    a[mi], bg[ni], accG[mi][ni], 0, 0, 0);
                accU[mi][ni] = __builtin_amdgcn_mfma_f32_16x16x32_bf16(
                    a[mi], bu[ni], accU[mi][ni], 0, 0, 0);
            }
        __syncthreads();
    }

    // epilogue: silu(g)*u -> bf16 act (compact rows)
#pragma unroll
    for (int mi = 0; mi < 4; mi++) {
#pragma unroll
        for (int r = 0; r < 4; r++) {
            int gm = m0 + wr * 64 + mi * 16 + (lane >> 4) * 4 + r;
            if (gm < mcnt) {
#pragma unroll
                for (int ni = 0; ni < 4; ni++) {
                    int col = n0 + wc * 64 + ni * 16 + lr;
                    float g = accG[mi][ni][r], u = accU[mi][ni][r];
                    act[(size_t)(base + gm) * INTER + col] = f2bf(silu_f(g) * u);
                }
            }
        }
    }
}

// ============ GEMM 2: out += w * (act @ Wd) ================================
// Tile 128Mx256N (32 MFMA per window), single-buf 24KB LDS, fragment-ordered,
// dense task-table dispatch, NO swizzle.
__global__ __launch_bounds__(256, 2) void gemm_down(
    const ushort_t* __restrict__ act, const ushort_t* __restrict__ WdT,
    float* __restrict__ out, const int* __restrict__ tok_of_row,
    const float* __restrict__ w_of_row, const int* __restrict__ offs2,
    const int* __restrict__ cnt2, const int* __restrict__ task_pm) {
    int tk = task_pm[blockIdx.y];
    if (tk < 0) return;
    int e = tk >> 16;
    int m0 = (tk & 0xffff) << 7;
    int bx = blockIdx.x;
    int mcnt = cnt2[e];
    int base = offs2[e];
    int n0 = bx * 256;
    const ushort_t* Bd = WdT + (size_t)e * HIDDEN * INTER;

    __shared__ short As[8 * 512];
    __shared__ short Bs[16 * 512];

    int tid = threadIdx.x;
    int wave = tid >> 6, lane = tid & 63;
    int wr = wave >> 1, wc = wave & 1;  // each wave: 64M x 128N
    int lr = lane & 15;
    int kq = (lane >> 4) * 8;

    // A rows compact; max staged row = base+m0+127 <= TROWS-1.
    const ushort_t* srcA0 = act + (size_t)(base + m0 + 32 * wave + lr) * INTER + kq;
    const ushort_t* srcA1 = srcA0 + (size_t)16 * INTER;
    const ushort_t* srcB0 = Bd + (size_t)(n0 + 64 * wave + lr) * INTER + kq;
    const ushort_t* srcB1 = srcB0 + (size_t)16 * INTER;
    const ushort_t* srcB2 = srcB0 + (size_t)32 * INTER;
    const ushort_t* srcB3 = srcB0 + (size_t)48 * INTER;

    f32x4 acc[4][8] = {};

    for (int k0 = 0; k0 < INTER; k0 += 32) {
        GLDS16(srcA0 + k0, &As[(2 * wave) * 512]);
        GLDS16(srcA1 + k0, &As[(2 * wave + 1) * 512]);
        GLDS16(srcB0 + k0, &Bs[(4 * wave) * 512]);
        GLDS16(srcB1 + k0, &Bs[(4 * wave + 1) * 512]);
        GLDS16(srcB2 + k0, &Bs[(4 * wave + 2) * 512]);
        GLDS16(srcB3 + k0, &Bs[(4 * wave + 3) * 512]);
        __syncthreads();
        short8 a[4], b[8];
#pragma unroll
        for (int mi = 0; mi < 4; mi++)
            a[mi] = *reinterpret_cast<const short8*>(
                &As[(wr * 4 + mi) * 512 + lane * 8]);
#pragma unroll
        for (int ni = 0; ni < 8; ni++)
            b[ni] = *reinterpret_cast<const short8*>(
                &Bs[(wc * 8 + ni) * 512 + lane * 8]);
#pragma unroll
        for (int mi = 0; mi < 4; mi++)
#pragma unroll
            for (int ni = 0; ni < 8; ni++)
                acc[mi][ni] = __builtin_amdgcn_mfma_f32_16x16x32_bf16(
                    a[mi], b[ni], acc[mi][ni], 0, 0, 0);
        __syncthreads();
    }

#pragma unroll
    for (int mi = 0; mi < 4; mi++) {
#pragma unroll
        for (int r = 0; r < 4; r++) {
            int gm = m0 + wr * 64 + mi * 16 + (lane >> 4) * 4 + r;
            if (gm < mcnt) {
                int tok = tok_of_row[base + gm] >> 1;
                float w = w_of_row[base + gm];
#pragma unroll
                for (int ni = 0; ni < 8; ni++) {
                    int col = n0 + wc * 128 + ni * 16 + lr;
                    atomicAdd(&out[(size_t)tok * HIDDEN + col], w * acc[mi][ni][r]);
                }
            }
        }
    }
}

extern "C" void kernel_launch(void* const* d_in, const int* in_sizes, int n_in,
                              void* d_out, int out_size, void* d_ws, size_t ws_size,
                              hipStream_t stream) {
    const float* x   = (const float*)d_in[0];
    const float* gw  = (const float*)d_in[1];
    const float* wg  = (const float*)d_in[2];
    const float* wu  = (const float*)d_in[3];
    const float* wd  = (const float*)d_in[4];
    const float* swg = (const float*)d_in[5];
    const float* swu = (const float*)d_in[6];
    const float* swd = (const float*)d_in[7];
    float* out = (float*)d_out;

    // ---- workspace layout (bf16 buffers first, 16B-aligned) ----
    const size_t XB   = (size_t)NTOK * HIDDEN;
    const size_t WPAN = (size_t)NPANEL * INTER * HIDDEN;
    const size_t ACT  = (size_t)TROWS * INTER;
    ushort_t* xb  = (ushort_t*)d_ws;
    ushort_t* wgT = xb + XB;
    ushort_t* wuT = wgT + WPAN;
    ushort_t* wdT = wuT + WPAN;
    ushort_t* act = wdT + WPAN;
    int* ib = (int*)(act + ACT);
    int* top_i      = ib;                 // NROWS
    int* rnk        = ib + NROWS;         // NROWS
    int* cnt        = ib + 2 * NROWS;     // 8
    int* offs2      = ib + 2 * NROWS + 8; // 16
    int* cnt2       = offs2 + 16;         // 16
    int* task_pm    = cnt2 + 16;          // MAXT
    int* tok_of_row = task_pm + MAXT;     // TROWS
    float* top_w    = (float*)(tok_of_row + TROWS);  // NROWS
    float* w_of_row = top_w + NROWS;                 // TROWS

    // ---- 1. dtype conversions (+ weight transposes to [N][K]) ----
    conv_x<<<(NTOK * HIDDEN) / (256 * 4), 256, 0, stream>>>(x, xb);
    dim3 tb(32, 8);
    tconv<<<dim3(INTER / 32, HIDDEN / 32, NEXP), tb, 0, stream>>>(
        wg, wgT, HIDDEN, INTER, (long)HIDDEN * INTER, (long)INTER * HIDDEN);
    tconv<<<dim3(INTER / 32, HIDDEN / 32, NEXP), tb, 0, stream>>>(
        wu, wuT, HIDDEN, INTER, (long)HIDDEN * INTER, (long)INTER * HIDDEN);
    tconv<<<dim3(SINTER / 32, HIDDEN / 32, 1), tb, 0, stream>>>(
        swg, wgT + (size_t)8 * INTER * HIDDEN, HIDDEN, SINTER, 0, 0);
    tconv<<<dim3(SINTER / 32, HIDDEN / 32, 1), tb, 0, stream>>>(
        swu, wuT + (size_t)8 * INTER * HIDDEN, HIDDEN, SINTER, 0, 0);
    tconv<<<dim3(HIDDEN / 32, INTER / 32, NEXP), tb, 0, stream>>>(
        wd, wdT, INTER, HIDDEN, (long)INTER * HIDDEN, (long)HIDDEN * INTER);
    tconv<<<dim3(HIDDEN / 32, INTER / 32, 2), tb, 0, stream>>>(
        swd, wdT + (size_t)8 * HIDDEN * INTER, INTER, HIDDEN,
        (long)INTER * HIDDEN, (long)HIDDEN * INTER);

    // ---- 2. gate + routing ----
    gate_kernel<<<NTOK, 64, 0, stream>>>(x, gw, top_i, top_w);
    hipMemsetAsync(cnt, 0, 8 * sizeof(int), stream);
    assign_kernel<<<NROWS / 256, 256, 0, stream>>>(top_i, cnt, rnk);
    scan_kernel<<<1, 1, 0, stream>>>(cnt, offs2, cnt2, task_pm);
    fill_kernel<<<NROWS / 256, 256, 0, stream>>>(top_i, top_w, rnk, offs2,
                                                 tok_of_row, w_of_row);
    fill_shared<<<NROWS / 256, 256, 0, stream>>>(tok_of_row, w_of_row);

    // ---- 3. grouped SwiGLU GEMMs, dense task-table dispatch ----
    gemm_gu<<<dim3(INTER / 128, MAXT), 256, 0, stream>>>(
        xb, wgT, wuT, act, tok_of_row, offs2, cnt2, task_pm);
    hipMemsetAsync(out, 0, (size_t)out_size * sizeof(float), stream);
    gemm_down<<<dim3(HIDDEN / 256, MAXT), 256, 0, stream>>>(
        act, wdT, out, tok_of_row, w_of_row, offs2, cnt2, task_pm);
}

// Round 8
// 396.997 us; speedup vs baseline: 1.6140x; 1.1183x over previous
//
#include <hip/hip_runtime.h>
#include <hip/hip_bf16.h>
#include <math.h>

#define HIDDEN 1024
#define NEXP 8
#define TOPK 2
#define INTER 1408
#define SINTER 2816
#define NTOK 4096
#define NROWS (NTOK * TOPK) /* 8192 routed rows */
#define NPANEL 10           /* 8 routed + 2 shared halves */
#define TROWS 16384         /* NROWS + 2*NTOK */
#define MAXT 136            /* max (panel, m-block) tasks */

typedef unsigned short ushort_t;
typedef __attribute__((ext_vector_type(8))) short short8;
typedef __attribute__((ext_vector_type(4))) float f32x4;

__device__ __forceinline__ ushort_t f2bf(float f) {
    unsigned int b = __float_as_uint(f);
    unsigned int r = (b + 0x7FFFu + ((b >> 16) & 1u)) >> 16;
    return (ushort_t)r;
}
__device__ __forceinline__ float bf2f(ushort_t u) {
    return __uint_as_float(((unsigned int)u) << 16);
}
__device__ __forceinline__ float silu_f(float g) {
    return g * (1.0f / (1.0f + __expf(-g)));
}
__device__ __forceinline__ int imin(int a, int b) { return a < b ? a : b; }

#define GLDS16(gp, lp) __builtin_amdgcn_global_load_lds(                     \
    (const __attribute__((address_space(1))) void*)(gp),                     \
    (__attribute__((address_space(3))) void*)(lp), 16, 0, 0)

// ---------------- fp32 -> bf16 elementwise (x) ----------------
__global__ void conv_x(const float* __restrict__ src, ushort_t* __restrict__ dst) {
    int i = (blockIdx.x * 256 + threadIdx.x) * 4;
    float4 v = *reinterpret_cast<const float4*>(&src[i]);
    union { ushort_t h[4]; unsigned long long ll; } p;
    p.h[0] = f2bf(v.x); p.h[1] = f2bf(v.y); p.h[2] = f2bf(v.z); p.h[3] = f2bf(v.w);
    *reinterpret_cast<unsigned long long*>(&dst[i]) = p.ll;
}

// ---- fp32 [R][C] -> bf16 [C][R] transpose-convert -------------------------
__global__ void tconv(const float* __restrict__ src, ushort_t* __restrict__ dst,
                      int R, int C, long sstride, long dstride) {
    src += (size_t)blockIdx.z * sstride;
    dst += (size_t)blockIdx.z * dstride;
    __shared__ float tile[32][33];
    int ct = blockIdx.x * 32, rt = blockIdx.y * 32;
    int tx = threadIdx.x, ty = threadIdx.y;  // 32 x 8
#pragma unroll
    for (int i = 0; i < 4; i++)
        tile[ty + 8 * i][tx] = src[(size_t)(rt + ty + 8 * i) * C + ct + tx];
    __syncthreads();
#pragma unroll
    for (int i = 0; i < 4; i++)
        dst[(size_t)(ct + ty + 8 * i) * R + rt + tx] = f2bf(tile[tx][ty + 8 * i]);
}

// ---------------- gate: logits -> softmax -> top2 -> normalized weights ----
__global__ void gate_kernel(const float* __restrict__ x, const float* __restrict__ gw,
                            int* __restrict__ top_i, float* __restrict__ top_w) {
    int t = blockIdx.x;
    int lane = threadIdx.x;
    const float* xr = x + (size_t)t * HIDDEN;
    float acc[NEXP];
#pragma unroll
    for (int e = 0; e < NEXP; e++) acc[e] = 0.f;
    for (int j = 0; j < HIDDEN / 64; j++) {
        float xv = xr[lane + 64 * j];
#pragma unroll
        for (int e = 0; e < NEXP; e++)
            acc[e] = fmaf(xv, gw[e * HIDDEN + lane + 64 * j], acc[e]);
    }
#pragma unroll
    for (int e = 0; e < NEXP; e++) {
        float v = acc[e];
        for (int off = 32; off > 0; off >>= 1) v += __shfl_xor(v, off, 64);
        acc[e] = v;
    }
    if (lane == 0) {
        float mx = acc[0];
        for (int e = 1; e < NEXP; e++) mx = fmaxf(mx, acc[e]);
        float s[NEXP];
        float sum = 0.f;
        for (int e = 0; e < NEXP; e++) { s[e] = __expf(acc[e] - mx); sum += s[e]; }
        float inv = 1.0f / sum;
        for (int e = 0; e < NEXP; e++) s[e] *= inv;
        int e0 = 0;
        for (int e = 1; e < NEXP; e++) if (s[e] > s[e0]) e0 = e;
        int e1 = -1;
        for (int e = 0; e < NEXP; e++) {
            if (e == e0) continue;
            if (e1 < 0 || s[e] > s[e1]) e1 = e;
        }
        float w0 = s[e0], w1 = s[e1];
        float denom = w0 + w1 + 1e-20f;
        top_i[t * 2 + 0] = e0;
        top_i[t * 2 + 1] = e1;
        top_w[t * 2 + 0] = w0 / denom;
        top_w[t * 2 + 1] = w1 / denom;
    }
}

// ---------------- routing bookkeeping ----------------
__global__ void assign_kernel(const int* __restrict__ top_i, int* __restrict__ cnt,
                              int* __restrict__ rnk) {
    int j = blockIdx.x * blockDim.x + threadIdx.x;
    if (j < NROWS) rnk[j] = atomicAdd(&cnt[top_i[j]], 1);
}

// builds offsets AND the dense (panel, m-block) task table
__global__ void scan_kernel(const int* __restrict__ cnt, int* __restrict__ offs2,
                            int* __restrict__ cnt2, int* __restrict__ task_pm) {
    if (threadIdx.x == 0) {
        int o = 0;
        for (int e = 0; e < NEXP; e++) { offs2[e] = o; cnt2[e] = cnt[e]; o += cnt[e]; }
        offs2[8] = NROWS;          cnt2[8] = NTOK;
        offs2[9] = NROWS + NTOK;   cnt2[9] = NTOK;
        offs2[10] = TROWS;
        int t = 0;
        for (int e = 0; e < NPANEL; e++)
            for (int m0 = 0; m0 < cnt2[e]; m0 += 128)
                task_pm[t++] = (e << 16) | (m0 >> 7);
        for (; t < MAXT; t++) task_pm[t] = -1;
    }
}

__global__ void fill_kernel(const int* __restrict__ top_i, const float* __restrict__ top_w,
                            const int* __restrict__ rnk, const int* __restrict__ offs2,
                            int* __restrict__ tok_of_row, float* __restrict__ w_of_row,
                            int* __restrict__ inv_row) {
    int j = blockIdx.x * blockDim.x + threadIdx.x;
    if (j < NROWS) {
        int row = offs2[top_i[j]] + rnk[j];
        tok_of_row[row] = j;  // token = j>>1
        w_of_row[row] = top_w[j];
        inv_row[j] = row;
    }
}

__global__ void fill_shared(int* __restrict__ tok_of_row) {
    int j = blockIdx.x * blockDim.x + threadIdx.x;  // 0..8191
    tok_of_row[NROWS + j] = (j & (NTOK - 1)) << 1;  // token = j mod 4096
}

// ============ GEMM 1: act = silu(x@Wg)*(x@Wu) ==============================
// 256 thr / 4 waves (2x2), tile 128Mx128N over BOTH Wg and Wu (32 MFMA per
// barrier window), BK=32, single-buffer 24KB LDS, fragment-ordered LDS,
// dense 1-D grid with XCD-chunked swizzle (n-major logical order so each
// XCD walks consecutive same-panel tasks -> B slab L2-resident).
__global__ __launch_bounds__(256, 2) void gemm_gu(
    const ushort_t* __restrict__ xb, const ushort_t* __restrict__ WgT,
    const ushort_t* __restrict__ WuT, ushort_t* __restrict__ act,
    const int* __restrict__ tok_of_row, const int* __restrict__ offs2,
    const int* __restrict__ cnt2, const int* __restrict__ task_pm) {
    int T = gridDim.x;  // MAXT * (INTER/128), divisible by 8
    int orig = blockIdx.x;
    int logical = (orig & 7) * (T >> 3) + (orig >> 3);
    int task = logical % MAXT;
    int nidx = logical / MAXT;
    int tk = task_pm[task];
    if (tk < 0) return;
    int e = tk >> 16;
    int m0 = (tk & 0xffff) << 7;
    int mcnt = cnt2[e];
    int base = offs2[e];
    int n0 = nidx * 128;
    const ushort_t* Bg = WgT + (size_t)e * INTER * HIDDEN;
    const ushort_t* Bu = WuT + (size_t)e * INTER * HIDDEN;

    __shared__ short As[8 * 512];
    __shared__ short Bgs[8 * 512];
    __shared__ short Bus[8 * 512];

    int tid = threadIdx.x;
    int wave = tid >> 6, lane = tid & 63;
    int wr = wave >> 1, wc = wave & 1;  // 2x2 waves, each 64x64
    int lr = lane & 15;
    int kq = (lane >> 4) * 8;  // k-chunk of this lane (8 bf16 = 16B)

    int r0 = m0 + 32 * wave + lr, r1 = r0 + 16;
    int rr0 = base + imin(r0, mcnt - 1);
    int rr1 = base + imin(r1, mcnt - 1);
    const ushort_t* srcA0 = xb + (size_t)(tok_of_row[rr0] >> 1) * HIDDEN + kq;
    const ushort_t* srcA1 = xb + (size_t)(tok_of_row[rr1] >> 1) * HIDDEN + kq;
    const ushort_t* srcBg0 = Bg + (size_t)(n0 + 32 * wave + lr) * HIDDEN + kq;
    const ushort_t* srcBg1 = srcBg0 + (size_t)16 * HIDDEN;
    const ushort_t* srcBu0 = Bu + (size_t)(n0 + 32 * wave + lr) * HIDDEN + kq;
    const ushort_t* srcBu1 = srcBu0 + (size_t)16 * HIDDEN;

    f32x4 accG[4][4] = {};
    f32x4 accU[4][4] = {};

    for (int k0 = 0; k0 < HIDDEN; k0 += 32) {
        GLDS16(srcA0 + k0, &As[(2 * wave) * 512]);
        GLDS16(srcA1 + k0, &As[(2 * wave + 1) * 512]);
        GLDS16(srcBg0 + k0, &Bgs[(2 * wave) * 512]);
        GLDS16(srcBg1 + k0, &Bgs[(2 * wave + 1) * 512]);
        GLDS16(srcBu0 + k0, &Bus[(2 * wave) * 512]);
        GLDS16(srcBu1 + k0, &Bus[(2 * wave + 1) * 512]);
        __syncthreads();
        short8 a[4], bg[4], bu[4];
#pragma unroll
        for (int mi = 0; mi < 4; mi++)
            a[mi] = *reinterpret_cast<const short8*>(
                &As[(wr * 4 + mi) * 512 + lane * 8]);
#pragma unroll
        for (int ni = 0; ni < 4; ni++) {
            bg[ni] = *reinterpret_cast<const short8*>(
                &Bgs[(wc * 4 + ni) * 512 + lane * 8]);
            bu[ni] = *reinterpret_cast<const short8*>(
                &Bus[(wc * 4 + ni) * 512 + lane * 8]);
        }
#pragma unroll
        for (int mi = 0; mi < 4; mi++)
#pragma unroll
            for (int ni = 0; ni < 4; ni++) {
                accG[mi][ni] = __builtin_amdgcn_mfma_f32_16x16x32_bf16(
                    a[mi], bg[ni], accG[mi][ni], 0, 0, 0);
                accU[mi][ni] = __builtin_amdgcn_mfma_f32_16x16x32_bf16(
                    a[mi], bu[ni], accU[mi][ni], 0, 0, 0);
            }
        __syncthreads();
    }

    // epilogue: silu(g)*u -> bf16 act (compact rows)
#pragma unroll
    for (int mi = 0; mi < 4; mi++) {
#pragma unroll
        for (int r = 0; r < 4; r++) {
            int gm = m0 + wr * 64 + mi * 16 + (lane >> 4) * 4 + r;
            if (gm < mcnt) {
#pragma unroll
                for (int ni = 0; ni < 4; ni++) {
                    int col = n0 + wc * 64 + ni * 16 + lr;
                    float g = accG[mi][ni][r], u = accU[mi][ni][r];
                    act[(size_t)(base + gm) * INTER + col] = f2bf(silu_f(g) * u);
                }
            }
        }
    }
}

// ============ GEMM 2: part = act @ Wd (compact rows, plain bf16 stores) ====
// Tile 128Mx256N (32 MFMA per window), single-buf 24KB LDS, fragment-ordered,
// dense 1-D grid with XCD-chunked swizzle. NO atomics.
__global__ __launch_bounds__(256, 2) void gemm_down(
    const ushort_t* __restrict__ act, const ushort_t* __restrict__ WdT,
    ushort_t* __restrict__ part, const int* __restrict__ offs2,
    const int* __restrict__ cnt2, const int* __restrict__ task_pm) {
    int T = gridDim.x;  // MAXT * (HIDDEN/256)
    int orig = blockIdx.x;
    int logical = (orig & 7) * (T >> 3) + (orig >> 3);
    int task = logical % MAXT;
    int nidx = logical / MAXT;
    int tk = task_pm[task];
    if (tk < 0) return;
    int e = tk >> 16;
    int m0 = (tk & 0xffff) << 7;
    int mcnt = cnt2[e];
    int base = offs2[e];
    int n0 = nidx * 256;
    const ushort_t* Bd = WdT + (size_t)e * HIDDEN * INTER;

    __shared__ short As[8 * 512];
    __shared__ short Bs[16 * 512];

    int tid = threadIdx.x;
    int wave = tid >> 6, lane = tid & 63;
    int wr = wave >> 1, wc = wave & 1;  // each wave: 64M x 128N
    int lr = lane & 15;
    int kq = (lane >> 4) * 8;

    // A rows compact; max staged row = base+m0+127 <= TROWS-1.
    const ushort_t* srcA0 = act + (size_t)(base + m0 + 32 * wave + lr) * INTER + kq;
    const ushort_t* srcA1 = srcA0 + (size_t)16 * INTER;
    const ushort_t* srcB0 = Bd + (size_t)(n0 + 64 * wave + lr) * INTER + kq;
    const ushort_t* srcB1 = srcB0 + (size_t)16 * INTER;
    const ushort_t* srcB2 = srcB0 + (size_t)32 * INTER;
    const ushort_t* srcB3 = srcB0 + (size_t)48 * INTER;

    f32x4 acc[4][8] = {};

    for (int k0 = 0; k0 < INTER; k0 += 32) {
        GLDS16(srcA0 + k0, &As[(2 * wave) * 512]);
        GLDS16(srcA1 + k0, &As[(2 * wave + 1) * 512]);
        GLDS16(srcB0 + k0, &Bs[(4 * wave) * 512]);
        GLDS16(srcB1 + k0, &Bs[(4 * wave + 1) * 512]);
        GLDS16(srcB2 + k0, &Bs[(4 * wave + 2) * 512]);
        GLDS16(srcB3 + k0, &Bs[(4 * wave + 3) * 512]);
        __syncthreads();
        short8 a[4], b[8];
#pragma unroll
        for (int mi = 0; mi < 4; mi++)
            a[mi] = *reinterpret_cast<const short8*>(
                &As[(wr * 4 + mi) * 512 + lane * 8]);
#pragma unroll
        for (int ni = 0; ni < 8; ni++)
            b[ni] = *reinterpret_cast<const short8*>(
                &Bs[(wc * 8 + ni) * 512 + lane * 8]);
#pragma unroll
        for (int mi = 0; mi < 4; mi++)
#pragma unroll
            for (int ni = 0; ni < 8; ni++)
                acc[mi][ni] = __builtin_amdgcn_mfma_f32_16x16x32_bf16(
                    a[mi], b[ni], acc[mi][ni], 0, 0, 0);
        __syncthreads();
    }

#pragma unroll
    for (int mi = 0; mi < 4; mi++) {
#pragma unroll
        for (int r = 0; r < 4; r++) {
            int gm = m0 + wr * 64 + mi * 16 + (lane >> 4) * 4 + r;
            if (gm < mcnt) {
#pragma unroll
                for (int ni = 0; ni < 8; ni++) {
                    int col = n0 + wc * 128 + ni * 16 + lr;
                    part[(size_t)(base + gm) * HIDDEN + col] = f2bf(acc[mi][ni][r]);
                }
            }
        }
    }
}

// ============ combine: out[t] = w0*part[r0] + w1*part[r1] + part[s8] + part[s9]
__global__ __launch_bounds__(256) void combine_kernel(
    const ushort_t* __restrict__ part, const int* __restrict__ inv_row,
    const float* __restrict__ w_of_row, float* __restrict__ out) {
    int t = blockIdx.x;
    int c = threadIdx.x * 4;
    int r0 = inv_row[2 * t], r1 = inv_row[2 * t + 1];
    float w0 = w_of_row[r0], w1 = w_of_row[r1];
    ushort4 a0 = *reinterpret_cast<const ushort4*>(&part[(size_t)r0 * HIDDEN + c]);
    ushort4 a1 = *reinterpret_cast<const ushort4*>(&part[(size_t)r1 * HIDDEN + c]);
    ushort4 a2 = *reinterpret_cast<const ushort4*>(&part[((size_t)NROWS + t) * HIDDEN + c]);
    ushort4 a3 = *reinterpret_cast<const ushort4*>(&part[((size_t)NROWS + NTOK + t) * HIDDEN + c]);
    float4 o;
    o.x = w0 * bf2f(a0.x) + w1 * bf2f(a1.x) + bf2f(a2.x) + bf2f(a3.x);
    o.y = w0 * bf2f(a0.y) + w1 * bf2f(a1.y) + bf2f(a2.y) + bf2f(a3.y);
    o.z = w0 * bf2f(a0.z) + w1 * bf2f(a1.z) + bf2f(a2.z) + bf2f(a3.z);
    o.w = w0 * bf2f(a0.w) + w1 * bf2f(a1.w) + bf2f(a2.w) + bf2f(a3.w);
    *reinterpret_cast<float4*>(&out[(size_t)t * HIDDEN + c]) = o;
}

extern "C" void kernel_launch(void* const* d_in, const int* in_sizes, int n_in,
                              void* d_out, int out_size, void* d_ws, size_t ws_size,
                              hipStream_t stream) {
    const float* x   = (const float*)d_in[0];
    const float* gw  = (const float*)d_in[1];
    const float* wg  = (const float*)d_in[2];
    const float* wu  = (const float*)d_in[3];
    const float* wd  = (const float*)d_in[4];
    const float* swg = (const float*)d_in[5];
    const float* swu = (const float*)d_in[6];
    const float* swd = (const float*)d_in[7];
    float* out = (float*)d_out;

    // ---- workspace layout (bf16 buffers first, 16B-aligned) ----
    const size_t XB   = (size_t)NTOK * HIDDEN;
    const size_t WPAN = (size_t)NPANEL * INTER * HIDDEN;
    const size_t ACT  = (size_t)TROWS * INTER;
    const size_t PART = (size_t)TROWS * HIDDEN;
    ushort_t* xb   = (ushort_t*)d_ws;
    ushort_t* wgT  = xb + XB;
    ushort_t* wuT  = wgT + WPAN;
    ushort_t* wdT  = wuT + WPAN;
    ushort_t* act  = wdT + WPAN;
    ushort_t* part = act + ACT;
    int* ib = (int*)(part + PART);
    int* top_i      = ib;                 // NROWS
    int* rnk        = ib + NROWS;         // NROWS
    int* cnt        = ib + 2 * NROWS;     // 8
    int* offs2      = ib + 2 * NROWS + 8; // 16
    int* cnt2       = offs2 + 16;         // 16
    int* task_pm    = cnt2 + 16;          // MAXT
    int* tok_of_row = task_pm + MAXT;     // TROWS
    int* inv_row    = tok_of_row + TROWS; // NROWS
    float* top_w    = (float*)(inv_row + NROWS);  // NROWS
    float* w_of_row = top_w + NROWS;              // TROWS

    // ---- 1. dtype conversions (+ weight transposes to [N][K]) ----
    conv_x<<<(NTOK * HIDDEN) / (256 * 4), 256, 0, stream>>>(x, xb);
    dim3 tb(32, 8);
    tconv<<<dim3(INTER / 32, HIDDEN / 32, NEXP), tb, 0, stream>>>(
        wg, wgT, HIDDEN, INTER, (long)HIDDEN * INTER, (long)INTER * HIDDEN);
    tconv<<<dim3(INTER / 32, HIDDEN / 32, NEXP), tb, 0, stream>>>(
        wu, wuT, HIDDEN, INTER, (long)HIDDEN * INTER, (long)INTER * HIDDEN);
    tconv<<<dim3(SINTER / 32, HIDDEN / 32, 1), tb, 0, stream>>>(
        swg, wgT + (size_t)8 * INTER * HIDDEN, HIDDEN, SINTER, 0, 0);
    tconv<<<dim3(SINTER / 32, HIDDEN / 32, 1), tb, 0, stream>>>(
        swu, wuT + (size_t)8 * INTER * HIDDEN, HIDDEN, SINTER, 0, 0);
    tconv<<<dim3(HIDDEN / 32, INTER / 32, NEXP), tb, 0, stream>>>(
        wd, wdT, INTER, HIDDEN, (long)INTER * HIDDEN, (long)HIDDEN * INTER);
    tconv<<<dim3(HIDDEN / 32, INTER / 32, 2), tb, 0, stream>>>(
        swd, wdT + (size_t)8 * HIDDEN * INTER, INTER, HIDDEN,
        (long)INTER * HIDDEN, (long)HIDDEN * INTER);

    // ---- 2. gate + routing ----
    gate_kernel<<<NTOK, 64, 0, stream>>>(x, gw, top_i, top_w);
    hipMemsetAsync(cnt, 0, 8 * sizeof(int), stream);
    assign_kernel<<<NROWS / 256, 256, 0, stream>>>(top_i, cnt, rnk);
    scan_kernel<<<1, 1, 0, stream>>>(cnt, offs2, cnt2, task_pm);
    fill_kernel<<<NROWS / 256, 256, 0, stream>>>(top_i, top_w, rnk, offs2,
                                                 tok_of_row, w_of_row, inv_row);
    fill_shared<<<NROWS / 256, 256, 0, stream>>>(tok_of_row);

    // ---- 3. grouped SwiGLU GEMMs (dense 1-D swizzled grids) ----
    gemm_gu<<<MAXT * (INTER / 128), 256, 0, stream>>>(
        xb, wgT, wuT, act, tok_of_row, offs2, cnt2, task_pm);
    gemm_down<<<MAXT * (HIDDEN / 256), 256, 0, stream>>>(
        act, wdT, part, offs2, cnt2, task_pm);
    combine_kernel<<<NTOK, 256, 0, stream>>>(part, inv_row, w_of_row, out);
}

// Round 9
// 383.680 us; speedup vs baseline: 1.6700x; 1.0347x over previous
//
#include <hip/hip_runtime.h>
#include <hip/hip_bf16.h>
#include <math.h>

#define HIDDEN 1024
#define NEXP 8
#define TOPK 2
#define INTER 1408
#define SINTER 2816
#define NTOK 4096
#define NROWS (NTOK * TOPK) /* 8192 routed rows */
#define NPANEL 10           /* 8 routed + 2 shared halves */
#define TROWS 16384         /* NROWS + 2*NTOK */
#define MAXT 136            /* max (panel, m-block) tasks */

typedef unsigned short ushort_t;
typedef __attribute__((ext_vector_type(8))) short short8;
typedef __attribute__((ext_vector_type(4))) float f32x4;

__device__ __forceinline__ ushort_t f2bf(float f) {
    unsigned int b = __float_as_uint(f);
    unsigned int r = (b + 0x7FFFu + ((b >> 16) & 1u)) >> 16;
    return (ushort_t)r;
}
__device__ __forceinline__ float bf2f(ushort_t u) {
    return __uint_as_float(((unsigned int)u) << 16);
}
__device__ __forceinline__ float silu_f(float g) {
    return g * (1.0f / (1.0f + __expf(-g)));
}
__device__ __forceinline__ int imin(int a, int b) { return a < b ? a : b; }

#define GLDS16(gp, lp) __builtin_amdgcn_global_load_lds(                     \
    (const __attribute__((address_space(1))) void*)(gp),                     \
    (__attribute__((address_space(3))) void*)(lp), 16, 0, 0)

// ---------------- fp32 -> bf16 elementwise (x) ----------------
__global__ void conv_x(const float* __restrict__ src, ushort_t* __restrict__ dst) {
    int i = (blockIdx.x * 256 + threadIdx.x) * 4;
    float4 v = *reinterpret_cast<const float4*>(&src[i]);
    union { ushort_t h[4]; unsigned long long ll; } p;
    p.h[0] = f2bf(v.x); p.h[1] = f2bf(v.y); p.h[2] = f2bf(v.z); p.h[3] = f2bf(v.w);
    *reinterpret_cast<unsigned long long*>(&dst[i]) = p.ll;
}

// ---- fp32 [R][C] -> bf16 [C][R] transpose-convert -------------------------
__global__ void tconv(const float* __restrict__ src, ushort_t* __restrict__ dst,
                      int R, int C, long sstride, long dstride) {
    src += (size_t)blockIdx.z * sstride;
    dst += (size_t)blockIdx.z * dstride;
    __shared__ float tile[32][33];
    int ct = blockIdx.x * 32, rt = blockIdx.y * 32;
    int tx = threadIdx.x, ty = threadIdx.y;  // 32 x 8
#pragma unroll
    for (int i = 0; i < 4; i++)
        tile[ty + 8 * i][tx] = src[(size_t)(rt + ty + 8 * i) * C + ct + tx];
    __syncthreads();
#pragma unroll
    for (int i = 0; i < 4; i++)
        dst[(size_t)(ct + ty + 8 * i) * R + rt + tx] = f2bf(tile[tx][ty + 8 * i]);
}

// ---------------- gate: logits -> softmax -> top2 -> normalized weights ----
__global__ void gate_kernel(const float* __restrict__ x, const float* __restrict__ gw,
                            int* __restrict__ top_i, float* __restrict__ top_w) {
    int t = blockIdx.x;
    int lane = threadIdx.x;
    const float* xr = x + (size_t)t * HIDDEN;
    float acc[NEXP];
#pragma unroll
    for (int e = 0; e < NEXP; e++) acc[e] = 0.f;
    for (int j = 0; j < HIDDEN / 64; j++) {
        float xv = xr[lane + 64 * j];
#pragma unroll
        for (int e = 0; e < NEXP; e++)
            acc[e] = fmaf(xv, gw[e * HIDDEN + lane + 64 * j], acc[e]);
    }
#pragma unroll
    for (int e = 0; e < NEXP; e++) {
        float v = acc[e];
        for (int off = 32; off > 0; off >>= 1) v += __shfl_xor(v, off, 64);
        acc[e] = v;
    }
    if (lane == 0) {
        float mx = acc[0];
        for (int e = 1; e < NEXP; e++) mx = fmaxf(mx, acc[e]);
        float s[NEXP];
        float sum = 0.f;
        for (int e = 0; e < NEXP; e++) { s[e] = __expf(acc[e] - mx); sum += s[e]; }
        float inv = 1.0f / sum;
        for (int e = 0; e < NEXP; e++) s[e] *= inv;
        int e0 = 0;
        for (int e = 1; e < NEXP; e++) if (s[e] > s[e0]) e0 = e;
        int e1 = -1;
        for (int e = 0; e < NEXP; e++) {
            if (e == e0) continue;
            if (e1 < 0 || s[e] > s[e1]) e1 = e;
        }
        float w0 = s[e0], w1 = s[e1];
        float denom = w0 + w1 + 1e-20f;
        top_i[t * 2 + 0] = e0;
        top_i[t * 2 + 1] = e1;
        top_w[t * 2 + 0] = w0 / denom;
        top_w[t * 2 + 1] = w1 / denom;
    }
}

// ---------------- routing bookkeeping ----------------
__global__ void assign_kernel(const int* __restrict__ top_i, int* __restrict__ cnt,
                              int* __restrict__ rnk) {
    int j = blockIdx.x * blockDim.x + threadIdx.x;
    if (j < NROWS) rnk[j] = atomicAdd(&cnt[top_i[j]], 1);
}

// builds offsets AND the dense (panel, m-block) task table
__global__ void scan_kernel(const int* __restrict__ cnt, int* __restrict__ offs2,
                            int* __restrict__ cnt2, int* __restrict__ task_pm) {
    if (threadIdx.x == 0) {
        int o = 0;
        for (int e = 0; e < NEXP; e++) { offs2[e] = o; cnt2[e] = cnt[e]; o += cnt[e]; }
        offs2[8] = NROWS;          cnt2[8] = NTOK;
        offs2[9] = NROWS + NTOK;   cnt2[9] = NTOK;
        offs2[10] = TROWS;
        int t = 0;
        for (int e = 0; e < NPANEL; e++)
            for (int m0 = 0; m0 < cnt2[e]; m0 += 128)
                task_pm[t++] = (e << 16) | (m0 >> 7);
        for (; t < MAXT; t++) task_pm[t] = -1;
    }
}

__global__ void fill_kernel(const int* __restrict__ top_i, const float* __restrict__ top_w,
                            const int* __restrict__ rnk, const int* __restrict__ offs2,
                            int* __restrict__ tok_of_row, float* __restrict__ w_of_row,
                            int* __restrict__ inv_row) {
    int j = blockIdx.x * blockDim.x + threadIdx.x;
    if (j < NROWS) {
        int row = offs2[top_i[j]] + rnk[j];
        tok_of_row[row] = j;  // token = j>>1
        w_of_row[row] = top_w[j];
        inv_row[j] = row;
    }
}

__global__ void fill_shared(int* __restrict__ tok_of_row) {
    int j = blockIdx.x * blockDim.x + threadIdx.x;  // 0..8191
    tok_of_row[NROWS + j] = (j & (NTOK - 1)) << 1;  // token = j mod 4096
}

// ============ GEMM 1: act = silu(x@Wg)*(x@Wu) ==============================
// 256 thr / 4 waves (2x2), tile 128Mx128N over BOTH Wg and Wu (32 MFMA per
// window), BK=32, fragment-ordered LDS, DOUBLE-buffered (48KB) with
// T4 counted-vmcnt prefetch: stage tile t+2 after reads of tile t; top of
// step waits vmcnt(6) so next tile's loads stay in flight (never drain to 0
// except the final step). Raw s_barrier + asm waitcnt + sched_barrier(0).
__global__ __launch_bounds__(256, 2) void gemm_gu(
    const ushort_t* __restrict__ xb, const ushort_t* __restrict__ WgT,
    const ushort_t* __restrict__ WuT, ushort_t* __restrict__ act,
    const int* __restrict__ tok_of_row, const int* __restrict__ offs2,
    const int* __restrict__ cnt2, const int* __restrict__ task_pm) {
    int T = gridDim.x;  // MAXT * (INTER/128), divisible by 8
    int orig = blockIdx.x;
    int logical = (orig & 7) * (T >> 3) + (orig >> 3);
    int task = logical % MAXT;
    int nidx = logical / MAXT;
    int tk = task_pm[task];
    if (tk < 0) return;
    int e = tk >> 16;
    int m0 = (tk & 0xffff) << 7;
    int mcnt = cnt2[e];
    int base = offs2[e];
    int n0 = nidx * 128;
    const ushort_t* Bg = WgT + (size_t)e * INTER * HIDDEN;
    const ushort_t* Bu = WuT + (size_t)e * INTER * HIDDEN;

    __shared__ short As[2 * 8 * 512];
    __shared__ short Bgs[2 * 8 * 512];
    __shared__ short Bus[2 * 8 * 512];

    int tid = threadIdx.x;
    int wave = tid >> 6, lane = tid & 63;
    int wr = wave >> 1, wc = wave & 1;  // 2x2 waves, each 64x64
    int lr = lane & 15;
    int kq = (lane >> 4) * 8;  // k-chunk of this lane (8 bf16 = 16B)

    int r0 = m0 + 32 * wave + lr, r1 = r0 + 16;
    int rr0 = base + imin(r0, mcnt - 1);
    int rr1 = base + imin(r1, mcnt - 1);
    const ushort_t* srcA0 = xb + (size_t)(tok_of_row[rr0] >> 1) * HIDDEN + kq;
    const ushort_t* srcA1 = xb + (size_t)(tok_of_row[rr1] >> 1) * HIDDEN + kq;
    const ushort_t* srcBg0 = Bg + (size_t)(n0 + 32 * wave + lr) * HIDDEN + kq;
    const ushort_t* srcBg1 = srcBg0 + (size_t)16 * HIDDEN;
    const ushort_t* srcBu0 = Bu + (size_t)(n0 + 32 * wave + lr) * HIDDEN + kq;
    const ushort_t* srcBu1 = srcBu0 + (size_t)16 * HIDDEN;

    f32x4 accG[4][4] = {};
    f32x4 accU[4][4] = {};

#define STAGE_GU(bo, k0)                                                     \
    do {                                                                     \
        GLDS16(srcA0 + (k0), &As[(bo) + (2 * wave) * 512]);                  \
        GLDS16(srcA1 + (k0), &As[(bo) + (2 * wave + 1) * 512]);              \
        GLDS16(srcBg0 + (k0), &Bgs[(bo) + (2 * wave) * 512]);                \
        GLDS16(srcBg1 + (k0), &Bgs[(bo) + (2 * wave + 1) * 512]);            \
        GLDS16(srcBu0 + (k0), &Bus[(bo) + (2 * wave) * 512]);                \
        GLDS16(srcBu1 + (k0), &Bus[(bo) + (2 * wave + 1) * 512]);            \
    } while (0)

    STAGE_GU(0, 0);
    STAGE_GU(4096, 32);

    const int NT = HIDDEN / 32;  // 32
    for (int t = 0; t < NT; t++) {
        int bo = (t & 1) << 12;  // *4096 elements
        if (t < NT - 1) asm volatile("s_waitcnt vmcnt(6)" ::: "memory");
        else            asm volatile("s_waitcnt vmcnt(0)" ::: "memory");
        __builtin_amdgcn_sched_barrier(0);
        __builtin_amdgcn_s_barrier();  // buf[t&1] ready for all waves
        short8 a[4], bg[4], bu[4];
#pragma unroll
        for (int mi = 0; mi < 4; mi++)
            a[mi] = *reinterpret_cast<const short8*>(
                &As[bo + (wr * 4 + mi) * 512 + lane * 8]);
#pragma unroll
        for (int ni = 0; ni < 4; ni++) {
            bg[ni] = *reinterpret_cast<const short8*>(
                &Bgs[bo + (wc * 4 + ni) * 512 + lane * 8]);
            bu[ni] = *reinterpret_cast<const short8*>(
                &Bus[bo + (wc * 4 + ni) * 512 + lane * 8]);
        }
        asm volatile("s_waitcnt lgkmcnt(0)" ::: "memory");
        __builtin_amdgcn_sched_barrier(0);
        __builtin_amdgcn_s_barrier();  // all reads of buf[t&1] done
        if (t + 2 < NT) STAGE_GU(bo, (t + 2) * 32);
        __builtin_amdgcn_s_setprio(1);
#pragma unroll
        for (int mi = 0; mi < 4; mi++)
#pragma unroll
            for (int ni = 0; ni < 4; ni++) {
                accG[mi][ni] = __builtin_amdgcn_mfma_f32_16x16x32_bf16(
                    a[mi], bg[ni], accG[mi][ni], 0, 0, 0);
                accU[mi][ni] = __builtin_amdgcn_mfma_f32_16x16x32_bf16(
                    a[mi], bu[ni], accU[mi][ni], 0, 0, 0);
            }
        __builtin_amdgcn_s_setprio(0);
    }
#undef STAGE_GU

    // epilogue: silu(g)*u -> bf16 act (compact rows)
#pragma unroll
    for (int mi = 0; mi < 4; mi++) {
#pragma unroll
        for (int r = 0; r < 4; r++) {
            int gm = m0 + wr * 64 + mi * 16 + (lane >> 4) * 4 + r;
            if (gm < mcnt) {
#pragma unroll
                for (int ni = 0; ni < 4; ni++) {
                    int col = n0 + wc * 64 + ni * 16 + lr;
                    float g = accG[mi][ni][r], u = accU[mi][ni][r];
                    act[(size_t)(base + gm) * INTER + col] = f2bf(silu_f(g) * u);
                }
            }
        }
    }
}

// ============ GEMM 2: part = act @ Wd (compact rows, plain bf16 stores) ====
// Tile 128Mx256N (32 MFMA/window), BK=32, double-buffered 48KB LDS, same
// counted-vmcnt prefetch pipeline. NO atomics.
__global__ __launch_bounds__(256, 2) void gemm_down(
    const ushort_t* __restrict__ act, const ushort_t* __restrict__ WdT,
    ushort_t* __restrict__ part, const int* __restrict__ offs2,
    const int* __restrict__ cnt2, const int* __restrict__ task_pm) {
    int T = gridDim.x;  // MAXT * (HIDDEN/256)
    int orig = blockIdx.x;
    int logical = (orig & 7) * (T >> 3) + (orig >> 3);
    int task = logical % MAXT;
    int nidx = logical / MAXT;
    int tk = task_pm[task];
    if (tk < 0) return;
    int e = tk >> 16;
    int m0 = (tk & 0xffff) << 7;
    int mcnt = cnt2[e];
    int base = offs2[e];
    int n0 = nidx * 256;
    const ushort_t* Bd = WdT + (size_t)e * HIDDEN * INTER;

    __shared__ short As[2 * 8 * 512];
    __shared__ short Bs[2 * 16 * 512];

    int tid = threadIdx.x;
    int wave = tid >> 6, lane = tid & 63;
    int wr = wave >> 1, wc = wave & 1;  // each wave: 64M x 128N
    int lr = lane & 15;
    int kq = (lane >> 4) * 8;

    // A rows compact; max staged row = base+m0+127 <= TROWS-1.
    const ushort_t* srcA0 = act + (size_t)(base + m0 + 32 * wave + lr) * INTER + kq;
    const ushort_t* srcA1 = srcA0 + (size_t)16 * INTER;
    const ushort_t* srcB0 = Bd + (size_t)(n0 + 64 * wave + lr) * INTER + kq;
    const ushort_t* srcB1 = srcB0 + (size_t)16 * INTER;
    const ushort_t* srcB2 = srcB0 + (size_t)32 * INTER;
    const ushort_t* srcB3 = srcB0 + (size_t)48 * INTER;

    f32x4 acc[4][8] = {};

#define STAGE_D(boA, boB, k0)                                                \
    do {                                                                     \
        GLDS16(srcA0 + (k0), &As[(boA) + (2 * wave) * 512]);                 \
        GLDS16(srcA1 + (k0), &As[(boA) + (2 * wave + 1) * 512]);             \
        GLDS16(srcB0 + (k0), &Bs[(boB) + (4 * wave) * 512]);                 \
        GLDS16(srcB1 + (k0), &Bs[(boB) + (4 * wave + 1) * 512]);             \
        GLDS16(srcB2 + (k0), &Bs[(boB) + (4 * wave + 2) * 512]);             \
        GLDS16(srcB3 + (k0), &Bs[(boB) + (4 * wave + 3) * 512]);             \
    } while (0)

    STAGE_D(0, 0, 0);
    STAGE_D(4096, 8192, 32);

    const int NT = INTER / 32;  // 44
    for (int t = 0; t < NT; t++) {
        int boA = (t & 1) << 12;  // *4096
        int boB = (t & 1) << 13;  // *8192
        if (t < NT - 1) asm volatile("s_waitcnt vmcnt(6)" ::: "memory");
        else            asm volatile("s_waitcnt vmcnt(0)" ::: "memory");
        __builtin_amdgcn_sched_barrier(0);
        __builtin_amdgcn_s_barrier();
        short8 a[4], b[8];
#pragma unroll
        for (int mi = 0; mi < 4; mi++)
            a[mi] = *reinterpret_cast<const short8*>(
                &As[boA + (wr * 4 + mi) * 512 + lane * 8]);
#pragma unroll
        for (int ni = 0; ni < 8; ni++)
            b[ni] = *reinterpret_cast<const short8*>(
                &Bs[boB + (wc * 8 + ni) * 512 + lane * 8]);
        asm volatile("s_waitcnt lgkmcnt(0)" ::: "memory");
        __builtin_amdgcn_sched_barrier(0);
        __builtin_amdgcn_s_barrier();
        if (t + 2 < NT) STAGE_D(boA, boB, (t + 2) * 32);
        __builtin_amdgcn_s_setprio(1);
#pragma unroll
        for (int mi = 0; mi < 4; mi++)
#pragma unroll
            for (int ni = 0; ni < 8; ni++)
                acc[mi][ni] = __builtin_amdgcn_mfma_f32_16x16x32_bf16(
                    a[mi], b[ni], acc[mi][ni], 0, 0, 0);
        __builtin_amdgcn_s_setprio(0);
    }
#undef STAGE_D

#pragma unroll
    for (int mi = 0; mi < 4; mi++) {
#pragma unroll
        for (int r = 0; r < 4; r++) {
            int gm = m0 + wr * 64 + mi * 16 + (lane >> 4) * 4 + r;
            if (gm < mcnt) {
#pragma unroll
                for (int ni = 0; ni < 8; ni++) {
                    int col = n0 + wc * 128 + ni * 16 + lr;
                    part[(size_t)(base + gm) * HIDDEN + col] = f2bf(acc[mi][ni][r]);
                }
            }
        }
    }
}

// ============ combine: out[t] = w0*part[r0] + w1*part[r1] + part[s8] + part[s9]
__global__ __launch_bounds__(256) void combine_kernel(
    const ushort_t* __restrict__ part, const int* __restrict__ inv_row,
    const float* __restrict__ w_of_row, float* __restrict__ out) {
    int t = blockIdx.x;
    int c = threadIdx.x * 4;
    int r0 = inv_row[2 * t], r1 = inv_row[2 * t + 1];
    float w0 = w_of_row[r0], w1 = w_of_row[r1];
    ushort4 a0 = *reinterpret_cast<const ushort4*>(&part[(size_t)r0 * HIDDEN + c]);
    ushort4 a1 = *reinterpret_cast<const ushort4*>(&part[(size_t)r1 * HIDDEN + c]);
    ushort4 a2 = *reinterpret_cast<const ushort4*>(&part[((size_t)NROWS + t) * HIDDEN + c]);
    ushort4 a3 = *reinterpret_cast<const ushort4*>(&part[((size_t)NROWS + NTOK + t) * HIDDEN + c]);
    float4 o;
    o.x = w0 * bf2f(a0.x) + w1 * bf2f(a1.x) + bf2f(a2.x) + bf2f(a3.x);
    o.y = w0 * bf2f(a0.y) + w1 * bf2f(a1.y) + bf2f(a2.y) + bf2f(a3.y);
    o.z = w0 * bf2f(a0.z) + w1 * bf2f(a1.z) + bf2f(a2.z) + bf2f(a3.z);
    o.w = w0 * bf2f(a0.w) + w1 * bf2f(a1.w) + bf2f(a2.w) + bf2f(a3.w);
    *reinterpret_cast<float4*>(&out[(size_t)t * HIDDEN + c]) = o;
}

extern "C" void kernel_launch(void* const* d_in, const int* in_sizes, int n_in,
                              void* d_out, int out_size, void* d_ws, size_t ws_size,
                              hipStream_t stream) {
    const float* x   = (const float*)d_in[0];
    const float* gw  = (const float*)d_in[1];
    const float* wg  = (const float*)d_in[2];
    const float* wu  = (const float*)d_in[3];
    const float* wd  = (const float*)d_in[4];
    const float* swg = (const float*)d_in[5];
    const float* swu = (const float*)d_in[6];
    const float* swd = (const float*)d_in[7];
    float* out = (float*)d_out;

    // ---- workspace layout (bf16 buffers first, 16B-aligned) ----
    const size_t XB   = (size_t)NTOK * HIDDEN;
    const size_t WPAN = (size_t)NPANEL * INTER * HIDDEN;
    const size_t ACT  = (size_t)TROWS * INTER;
    const size_t PART = (size_t)TROWS * HIDDEN;
    ushort_t* xb   = (ushort_t*)d_ws;
    ushort_t* wgT  = xb + XB;
    ushort_t* wuT  = wgT + WPAN;
    ushort_t* wdT  = wuT + WPAN;
    ushort_t* act  = wdT + WPAN;
    ushort_t* part = act + ACT;
    int* ib = (int*)(part + PART);
    int* top_i      = ib;                 // NROWS
    int* rnk        = ib + NROWS;         // NROWS
    int* cnt        = ib + 2 * NROWS;     // 8
    int* offs2      = ib + 2 * NROWS + 8; // 16
    int* cnt2       = offs2 + 16;         // 16
    int* task_pm    = cnt2 + 16;          // MAXT
    int* tok_of_row = task_pm + MAXT;     // TROWS
    int* inv_row    = tok_of_row + TROWS; // NROWS
    float* top_w    = (float*)(inv_row + NROWS);  // NROWS
    float* w_of_row = top_w + NROWS;              // TROWS

    // ---- 1. dtype conversions (+ weight transposes to [N][K]) ----
    conv_x<<<(NTOK * HIDDEN) / (256 * 4), 256, 0, stream>>>(x, xb);
    dim3 tb(32, 8);
    tconv<<<dim3(INTER / 32, HIDDEN / 32, NEXP), tb, 0, stream>>>(
        wg, wgT, HIDDEN, INTER, (long)HIDDEN * INTER, (long)INTER * HIDDEN);
    tconv<<<dim3(INTER / 32, HIDDEN / 32, NEXP), tb, 0, stream>>>(
        wu, wuT, HIDDEN, INTER, (long)HIDDEN * INTER, (long)INTER * HIDDEN);
    tconv<<<dim3(SINTER / 32, HIDDEN / 32, 1), tb, 0, stream>>>(
        swg, wgT + (size_t)8 * INTER * HIDDEN, HIDDEN, SINTER, 0, 0);
    tconv<<<dim3(SINTER / 32, HIDDEN / 32, 1), tb, 0, stream>>>(
        swu, wuT + (size_t)8 * INTER * HIDDEN, HIDDEN, SINTER, 0, 0);
    tconv<<<dim3(HIDDEN / 32, INTER / 32, NEXP), tb, 0, stream>>>(
        wd, wdT, INTER, HIDDEN, (long)INTER * HIDDEN, (long)HIDDEN * INTER);
    tconv<<<dim3(HIDDEN / 32, INTER / 32, 2), tb, 0, stream>>>(
        swd, wdT + (size_t)8 * HIDDEN * INTER, INTER, HIDDEN,
        (long)INTER * HIDDEN, (long)HIDDEN * INTER);

    // ---- 2. gate + routing ----
    gate_kernel<<<NTOK, 64, 0, stream>>>(x, gw, top_i, top_w);
    hipMemsetAsync(cnt, 0, 8 * sizeof(int), stream);
    assign_kernel<<<NROWS / 256, 256, 0, stream>>>(top_i, cnt, rnk);
    scan_kernel<<<1, 1, 0, stream>>>(cnt, offs2, cnt2, task_pm);
    fill_kernel<<<NROWS / 256, 256, 0, stream>>>(top_i, top_w, rnk, offs2,
                                                 tok_of_row, w_of_row, inv_row);
    fill_shared<<<NROWS / 256, 256, 0, stream>>>(tok_of_row);

    // ---- 3. grouped SwiGLU GEMMs (dense 1-D swizzled grids) ----
    gemm_gu<<<MAXT * (INTER / 128), 256, 0, stream>>>(
        xb, wgT, wuT, act, tok_of_row, offs2, cnt2, task_pm);
    gemm_down<<<MAXT * (HIDDEN / 256), 256, 0, stream>>>(
        act, wdT, part, offs2, cnt2, task_pm);
    combine_kernel<<<NTOK, 256, 0, stream>>>(part, inv_row, w_of_row, out);
}